// Round 1
// baseline (9093.603 us; speedup 1.0000x reference)
//
#include <hip/hip_runtime.h>
#include <math.h>

// ---- problem constants ----
constexpr int kB   = 8;
constexpr int kT   = 2048;
constexpr int kBT  = kB * kT;      // 16384
constexpr int DM   = 256;          // d_model
constexpr int DI   = 512;          // d_inner
constexpr int DS   = 64;           // d_state
constexpr int DR   = 16;           // dt_rank
constexpr int NF   = 15;           // nfeat
constexpr int HID  = 128;
constexpr int NBUCK= 15;
constexpr int NLAY = 4;
constexpr int DBLW = DR + 2*DS;    // 144

// ---------- helpers ----------
__device__ __forceinline__ float wave_sum64(float v) {
#pragma unroll
    for (int off = 32; off > 0; off >>= 1) v += __shfl_xor(v, off, 64);
    return v;
}
__device__ __forceinline__ float wave_max64(float v) {
#pragma unroll
    for (int off = 32; off > 0; off >>= 1) v = fmaxf(v, __shfl_xor(v, off, 64));
    return v;
}
// 256-thread block sum (4 waves), red must be float[4] shared
__device__ __forceinline__ float block_sum256(float v, float* red) {
    int tid = threadIdx.x;
    v = wave_sum64(v);
    if ((tid & 63) == 0) red[tid >> 6] = v;
    __syncthreads();
    float r = (red[0] + red[1]) + (red[2] + red[3]);
    __syncthreads();
    return r;
}
__device__ __forceinline__ float block_max256(float v, float* red) {
    int tid = threadIdx.x;
    v = wave_max64(v);
    if ((tid & 63) == 0) red[tid >> 6] = v;
    __syncthreads();
    float r = fmaxf(fmaxf(red[0], red[1]), fmaxf(red[2], red[3]));
    __syncthreads();
    return r;
}
__device__ __forceinline__ float gelu_exact(float x) {
    return 0.5f * x * (1.f + erff(x * 0.7071067811865476f));
}
__device__ __forceinline__ float softplus_f(float x) {
    return fmaxf(x, 0.f) + log1pf(expf(-fabsf(x)));
}
__device__ __forceinline__ float silu_f(float x) {
    return x / (1.f + expf(-x));
}

// ---------- bp stage 1: bars @ w1^T + b1 -> LN -> gelu ----------
__global__ __launch_bounds__(256) void bp1_kernel(
    const float* __restrict__ bars, const float* __restrict__ w1,
    const float* __restrict__ b1, const float* __restrict__ g1,
    const float* __restrict__ be1, float* __restrict__ out)
{
    __shared__ float s_in[NF];
    __shared__ float red[4];
    int row = blockIdx.x, tid = threadIdx.x;
    if (tid < NF) s_in[tid] = bars[row * NF + tid];
    __syncthreads();
    float acc = b1[tid];
#pragma unroll
    for (int k = 0; k < NF; k++) acc += s_in[k] * w1[tid * NF + k];
    float mean = block_sum256(acc, red) * (1.f / 256.f);
    float d = acc - mean;
    float var = block_sum256(d * d, red) * (1.f / 256.f);
    float nv = d * rsqrtf(var + 1e-5f) * g1[tid] + be1[tid];
    out[row * 256 + tid] = gelu_exact(nv);
}

// ---------- LN (+mask) ----------
__global__ __launch_bounds__(256) void ln_mask_kernel(
    const float* __restrict__ in, const float* __restrict__ g,
    const float* __restrict__ be, const float* __restrict__ mask,
    float* __restrict__ out)
{
    __shared__ float red[4];
    int row = blockIdx.x, tid = threadIdx.x;
    float v = in[row * 256 + tid];
    float mean = block_sum256(v, red) * (1.f / 256.f);
    float d = v - mean;
    float var = block_sum256(d * d, red) * (1.f / 256.f);
    float nv = d * rsqrtf(var + 1e-5f) * g[tid] + be[tid];
    out[row * 256 + tid] = nv * mask[row];
}

// ---------- LN + residual (X = LN(in)+X) ----------
__global__ __launch_bounds__(256) void ln_res_kernel(
    const float* __restrict__ in, const float* __restrict__ g,
    const float* __restrict__ be, float* __restrict__ X)
{
    __shared__ float red[4];
    int row = blockIdx.x, tid = threadIdx.x;
    float v = in[row * 256 + tid];
    float mean = block_sum256(v, red) * (1.f / 256.f);
    float d = v - mean;
    float var = block_sum256(d * d, red) * (1.f / 256.f);
    float nv = d * rsqrtf(var + 1e-5f) * g[tid] + be[tid];
    X[row * 256 + tid] = nv + X[row * 256 + tid];
}

// ---------- generic tiled GEMM: C[m,n] = sum_k A[m*lda+k]*W[n*K+k] (+bias) ----------
// act: 0 none, 1 softplus
__global__ __launch_bounds__(256) void gemm_nt(
    const float* __restrict__ A, int lda,
    const float* __restrict__ W,
    const float* __restrict__ bias,
    float* __restrict__ C, int ldc,
    int N, int K, int act)
{
    __shared__ float As[64][17];
    __shared__ float Ws[64][17];
    int tid = threadIdx.x;
    int tx = tid & 15, ty = tid >> 4;
    int bm = blockIdx.y * 64, bn = blockIdx.x * 64;
    float acc[4][4] = {};
    for (int kb = 0; kb < K; kb += 16) {
#pragma unroll
        for (int i = 0; i < 4; i++) {
            int idx = i * 256 + tid;
            int r = idx >> 4, kk = idx & 15;
            As[r][kk] = A[(bm + r) * lda + kb + kk];
        }
#pragma unroll
        for (int i = 0; i < 4; i++) {
            int idx = i * 256 + tid;
            int r = idx >> 4, kk = idx & 15;
            int n = bn + r;
            Ws[r][kk] = (n < N) ? W[n * K + kb + kk] : 0.f;
        }
        __syncthreads();
#pragma unroll
        for (int kk = 0; kk < 16; kk++) {
            float a0 = As[ty][kk], a1 = As[ty + 16][kk], a2 = As[ty + 32][kk], a3 = As[ty + 48][kk];
            float w0 = Ws[tx][kk], w1 = Ws[tx + 16][kk], w2 = Ws[tx + 32][kk], w3 = Ws[tx + 48][kk];
            acc[0][0] += a0 * w0; acc[0][1] += a0 * w1; acc[0][2] += a0 * w2; acc[0][3] += a0 * w3;
            acc[1][0] += a1 * w0; acc[1][1] += a1 * w1; acc[1][2] += a1 * w2; acc[1][3] += a1 * w3;
            acc[2][0] += a2 * w0; acc[2][1] += a2 * w1; acc[2][2] += a2 * w2; acc[2][3] += a2 * w3;
            acc[3][0] += a3 * w0; acc[3][1] += a3 * w1; acc[3][2] += a3 * w2; acc[3][3] += a3 * w3;
        }
        __syncthreads();
    }
#pragma unroll
    for (int i = 0; i < 4; i++) {
        int row = bm + ty + i * 16;
#pragma unroll
        for (int j = 0; j < 4; j++) {
            int col = bn + tx + j * 16;
            if (col < N) {
                float v = acc[i][j];
                if (bias) v += bias[col];
                if (act == 1) v = softplus_f(v);
                C[row * ldc + col] = v;
            }
        }
    }
}

// ---------- depthwise causal conv(4) + bias + silu ----------
__global__ __launch_bounds__(256) void conv_silu_kernel(
    const float* __restrict__ XZ, const float* __restrict__ cw,
    const float* __restrict__ cb, float* __restrict__ XC)
{
    int idx = blockIdx.x * 256 + threadIdx.x;   // over kBT*DI
    int d = idx & (DI - 1);
    int bt = idx >> 9;
    int t = bt & (kT - 1);
    float acc = cb[d];
#pragma unroll
    for (int k = 0; k < 4; k++) {
        int tt = t + k - 3;
        if (tt >= 0) acc += XZ[(bt + k - 3) * (2 * DI) + d] * cw[d * 4 + k];
    }
    XC[bt * DI + d] = silu_f(acc);
}

// ---------- selective scan: one wave per (b,d), lane = state ----------
__global__ __launch_bounds__(256) void scan_kernel(
    const float* __restrict__ DTp, const float* __restrict__ XC,
    const float* __restrict__ DBL, const float* __restrict__ Alog,
    const float* __restrict__ Dp, float* __restrict__ XZ)
{
    int wid = blockIdx.x * 4 + (threadIdx.x >> 6);   // 0..4095
    int lane = threadIdx.x & 63;
    int b = wid >> 9;          // /512
    int d = wid & (DI - 1);
    // a' = A * log2(e) so exp(dt*A) = exp2(dt*a')
    float a2 = -expf(Alog[d * DS + lane]) * 1.4426950408889634f;
    float Dd = Dp[d];
    float h = 0.f;
    int base = b * kT;
    for (int t = 0; t < kT; t++) {
        int bt = base + t;
        float dtv = DTp[bt * DI + d];
        float xv  = XC[bt * DI + d];
        float Bv  = DBL[bt * DBLW + DR + lane];
        float Cv  = DBL[bt * DBLW + DR + DS + lane];
        float dA  = exp2f(dtv * a2);
        h = dA * h + (dtv * xv) * Bv;
        float p = wave_sum64(h * Cv);
        float z = XZ[bt * (2 * DI) + DI + d];
        float y = (p + xv * Dd) * (z / (1.f + __expf(-z)));
        if (lane == 0) XZ[bt * (2 * DI) + d] = y;
    }
}

// ---------- pooling ----------
__global__ __launch_bounds__(256) void pool_logits_kernel(
    const float* __restrict__ X, const float* __restrict__ pw,
    const float* __restrict__ pb, float* __restrict__ LG)
{
    int wid = blockIdx.x * 4 + (threadIdx.x >> 6);  // row in [0,kBT)
    int lane = threadIdx.x & 63;
    float acc = 0.f;
#pragma unroll
    for (int c = 0; c < 4; c++) {
        int k = lane + 64 * c;
        acc += X[(size_t)wid * 256 + k] * pw[k];
    }
    acc = wave_sum64(acc);
    if (lane == 0) LG[wid] = acc + pb[0];
}

__global__ __launch_bounds__(256) void softmax_T_kernel(float* __restrict__ LG)
{
    __shared__ float red[4];
    int b = blockIdx.x, tid = threadIdx.x;
    float l[8];
    float m = -1e30f;
#pragma unroll
    for (int c = 0; c < 8; c++) {
        l[c] = LG[b * kT + tid + 256 * c];
        m = fmaxf(m, l[c]);
    }
    m = block_max256(m, red);
    float s = 0.f;
#pragma unroll
    for (int c = 0; c < 8; c++) { l[c] = expf(l[c] - m); s += l[c]; }
    s = block_sum256(s, red);
    float inv = 1.f / s;
#pragma unroll
    for (int c = 0; c < 8; c++) LG[b * kT + tid + 256 * c] = l[c] * inv;
}

__global__ __launch_bounds__(1024) void hp_kernel(
    const float* __restrict__ WTS, const float* __restrict__ X,
    float* __restrict__ HP)
{
    __shared__ float part[4][256];
    int b = blockIdx.x;
    int n = threadIdx.x & 255, c = threadIdx.x >> 8;
    float acc = 0.f;
    int t0 = c * 512;
    for (int t = t0; t < t0 + 512; t++) {
        int bt = b * kT + t;
        acc += WTS[bt] * X[(size_t)bt * 256 + n];
    }
    part[c][n] = acc;
    __syncthreads();
    if (c == 0) HP[b * 256 + n] = part[0][n] + part[1][n] + part[2][n] + part[3][n];
}

// ---------- heads (128 threads / block, 1 block per batch) ----------
__device__ __forceinline__ float ln128_gelu(float v, const float* g, const float* be, float* red)
{
    int tid = threadIdx.x;
    red[tid] = v; __syncthreads();
#pragma unroll
    for (int s = 64; s > 0; s >>= 1) { if (tid < s) red[tid] += red[tid + s]; __syncthreads(); }
    float mean = red[0] * (1.f / 128.f); __syncthreads();
    float d = v - mean;
    red[tid] = d * d; __syncthreads();
#pragma unroll
    for (int s = 64; s > 0; s >>= 1) { if (tid < s) red[tid] += red[tid + s]; __syncthreads(); }
    float var = red[0] * (1.f / 128.f); __syncthreads();
    float nv = d * rsqrtf(var + 1e-5f) * g[tid] + be[tid];
    return gelu_exact(nv);
}

__global__ __launch_bounds__(128) void head_kernel(
    const float* __restrict__ HP,
    const float* __restrict__ h_w1, const float* __restrict__ h_b1,
    const float* __restrict__ h_g1, const float* __restrict__ h_be1,
    const float* __restrict__ h_w2, const float* __restrict__ h_b2,
    const float* __restrict__ h_g2, const float* __restrict__ h_be2,
    const float* __restrict__ h_w3, const float* __restrict__ h_b3,
    const float* __restrict__ c_w1, const float* __restrict__ c_b1,
    const float* __restrict__ c_g1, const float* __restrict__ c_be1,
    const float* __restrict__ c_w2, const float* __restrict__ c_b2,
    float* __restrict__ out)
{
    __shared__ float s_hp[256];
    __shared__ float s1[128];
    __shared__ float red[128];
    int b = blockIdx.x, tid = threadIdx.x;
    s_hp[tid] = HP[b * 256 + tid];
    s_hp[tid + 128] = HP[b * 256 + tid + 128];
    __syncthreads();

    // h branch layer 1
    float v = h_b1[tid];
    for (int k = 0; k < 256; k++) v += s_hp[k] * h_w1[tid * 256 + k];
    float g1v = ln128_gelu(v, h_g1, h_be1, red);
    s1[tid] = g1v;
    __syncthreads();

    // h branch layer 2
    float v2 = h_b2[tid];
    for (int k = 0; k < 128; k++) v2 += s1[k] * h_w2[tid * 128 + k];
    float g2v = ln128_gelu(v2, h_g2, h_be2, red);

    // vix = dot(g2v, h_w3) + b3
    red[tid] = g2v * h_w3[tid];
    __syncthreads();
#pragma unroll
    for (int s = 64; s > 0; s >>= 1) { if (tid < s) red[tid] += red[tid + s]; __syncthreads(); }
    if (tid == 0) out[b] = red[0] + h_b3[0];
    __syncthreads();

    // c branch
    float vc = c_b1[tid];
    for (int k = 0; k < 256; k++) vc += s_hp[k] * c_w1[tid * 256 + k];
    float gcv = ln128_gelu(vc, c_g1, c_be1, red);
    s1[tid] = gcv;
    __syncthreads();
    if (tid < NBUCK) {
        float acc = c_b2[tid];
        for (int k = 0; k < 128; k++) acc += s1[k] * c_w2[tid * 128 + k];
        out[8 + b * NBUCK + tid] = acc;
    }
}

// ---------- launch ----------
extern "C" void kernel_launch(void* const* d_in, const int* in_sizes, int n_in,
                              void* d_out, int out_size, void* d_ws, size_t ws_size,
                              hipStream_t stream)
{
    const float* bars     = (const float*)d_in[0];
    const float* bar_mask = (const float*)d_in[1];
    const float* bp_w1    = (const float*)d_in[2];
    const float* bp_b1    = (const float*)d_in[3];
    const float* bp_g1    = (const float*)d_in[4];
    const float* bp_be1   = (const float*)d_in[5];
    const float* bp_w2    = (const float*)d_in[6];
    const float* bp_b2    = (const float*)d_in[7];
    const float* bp_g2    = (const float*)d_in[8];
    const float* bp_be2   = (const float*)d_in[9];
    const float* m_in_w   = (const float*)d_in[10];
    const float* m_conv_w = (const float*)d_in[11];
    const float* m_conv_b = (const float*)d_in[12];
    const float* m_xproj_w= (const float*)d_in[13];
    const float* m_dt_w   = (const float*)d_in[14];
    const float* m_dt_b   = (const float*)d_in[15];
    const float* m_Alog   = (const float*)d_in[16];
    const float* m_D      = (const float*)d_in[17];
    const float* m_out_w  = (const float*)d_in[18];
    const float* m_ln_g   = (const float*)d_in[19];
    const float* m_ln_b   = (const float*)d_in[20];
    const float* pool_w   = (const float*)d_in[21];
    const float* pool_b   = (const float*)d_in[22];
    const float* h_w1     = (const float*)d_in[23];
    const float* h_b1     = (const float*)d_in[24];
    const float* h_g1     = (const float*)d_in[25];
    const float* h_be1    = (const float*)d_in[26];
    const float* h_w2     = (const float*)d_in[27];
    const float* h_b2     = (const float*)d_in[28];
    const float* h_g2     = (const float*)d_in[29];
    const float* h_be2    = (const float*)d_in[30];
    const float* h_w3     = (const float*)d_in[31];
    const float* h_b3     = (const float*)d_in[32];
    const float* c_w1     = (const float*)d_in[33];
    const float* c_b1     = (const float*)d_in[34];
    const float* c_g1     = (const float*)d_in[35];
    const float* c_be1    = (const float*)d_in[36];
    const float* c_w2     = (const float*)d_in[37];
    const float* c_b2     = (const float*)d_in[38];
    float* out = (float*)d_out;

    float* ws = (float*)d_ws;
    float* X   = ws;                       // kBT*256
    float* XZ  = X   + (size_t)kBT * 256;  // kBT*1024
    float* XC  = XZ  + (size_t)kBT * 1024; // kBT*512
    float* DBL = XC  + (size_t)kBT * 512;  // kBT*144
    float* DTb = DBL + (size_t)kBT * DBLW; // kBT*512
    float* OUT = DTb + (size_t)kBT * 512;  // kBT*256
    float* LG  = OUT + (size_t)kBT * 256;  // kBT
    float* HP  = LG  + (size_t)kBT;        // kB*256

    // bar projection
    bp1_kernel<<<kBT, 256, 0, stream>>>(bars, bp_w1, bp_b1, bp_g1, bp_be1, OUT);
    gemm_nt<<<dim3(4, kBT / 64), 256, 0, stream>>>(OUT, 256, bp_w2, bp_b2, XC, 256, 256, 256, 0);
    ln_mask_kernel<<<kBT, 256, 0, stream>>>(XC, bp_g2, bp_be2, bar_mask, X);

    for (int i = 0; i < NLAY; i++) {
        const float* in_w  = m_in_w   + (size_t)i * 2 * DI * DM;
        const float* cw    = m_conv_w + (size_t)i * DI * 4;
        const float* cb    = m_conv_b + (size_t)i * DI;
        const float* xpw   = m_xproj_w+ (size_t)i * DBLW * DI;
        const float* dtw   = m_dt_w   + (size_t)i * DI * DR;
        const float* dtb   = m_dt_b   + (size_t)i * DI;
        const float* alog  = m_Alog   + (size_t)i * DI * DS;
        const float* dp    = m_D      + (size_t)i * DI;
        const float* outw  = m_out_w  + (size_t)i * DM * DI;
        const float* lng   = m_ln_g   + (size_t)i * DM;
        const float* lnb   = m_ln_b   + (size_t)i * DM;

        // xz = x @ in_w^T   (N=1024, K=256)
        gemm_nt<<<dim3(16, kBT / 64), 256, 0, stream>>>(X, 256, in_w, nullptr, XZ, 1024, 1024, 256, 0);
        // depthwise conv + silu -> XC
        conv_silu_kernel<<<(kBT * DI) / 256, 256, 0, stream>>>(XZ, cw, cb, XC);
        // dbl = XC @ xproj^T (N=144, K=512)
        gemm_nt<<<dim3(3, kBT / 64), 256, 0, stream>>>(XC, 512, xpw, nullptr, DBL, DBLW, DBLW, 512, 0);
        // dt = softplus(dbl[:, :16] @ dt_w^T + dt_b) (N=512, K=16)
        gemm_nt<<<dim3(8, kBT / 64), 256, 0, stream>>>(DBL, DBLW, dtw, dtb, DTb, 512, 512, 16, 1);
        // selective scan + gating, writes gated y into XZ[:, :512]
        scan_kernel<<<1024, 256, 0, stream>>>(DTb, XC, DBL, alog, dp, XZ);
        // out = y @ out_w^T (N=256, K=512)
        gemm_nt<<<dim3(4, kBT / 64), 256, 0, stream>>>(XZ, 1024, outw, nullptr, OUT, 256, 256, 512, 0);
        // x = LN(out) + x
        ln_res_kernel<<<kBT, 256, 0, stream>>>(OUT, lng, lnb, X);
    }

    // pooling
    pool_logits_kernel<<<kBT / 4, 256, 0, stream>>>(X, pool_w, pool_b, LG);
    softmax_T_kernel<<<kB, 256, 0, stream>>>(LG);
    hp_kernel<<<kB, 1024, 0, stream>>>(LG, X, HP);

    // heads
    head_kernel<<<kB, 128, 0, stream>>>(HP,
        h_w1, h_b1, h_g1, h_be1, h_w2, h_b2, h_g2, h_be2, h_w3, h_b3,
        c_w1, c_b1, c_g1, c_be1, c_w2, c_b2, out);
}

// Round 2
// 5063.886 us; speedup vs baseline: 1.7958x; 1.7958x over previous
//
#include <hip/hip_runtime.h>
#include <math.h>

// ---- problem constants ----
constexpr int kB   = 8;
constexpr int kT   = 2048;
constexpr int kBT  = kB * kT;      // 16384
constexpr int DM   = 256;          // d_model
constexpr int DI   = 512;          // d_inner
constexpr int DS   = 64;           // d_state
constexpr int DR   = 16;           // dt_rank
constexpr int NF   = 15;           // nfeat
constexpr int HID  = 128;
constexpr int NBUCK= 15;
constexpr int NLAY = 4;
constexpr int DBLW = DR + 2*DS;    // 144

// ---------- helpers ----------
__device__ __forceinline__ float wave_sum64(float v) {
#pragma unroll
    for (int off = 32; off > 0; off >>= 1) v += __shfl_xor(v, off, 64);
    return v;
}
__device__ __forceinline__ float wave_max64(float v) {
#pragma unroll
    for (int off = 32; off > 0; off >>= 1) v = fmaxf(v, __shfl_xor(v, off, 64));
    return v;
}
// 256-thread block sum (4 waves), red must be float[4] shared
__device__ __forceinline__ float block_sum256(float v, float* red) {
    int tid = threadIdx.x;
    v = wave_sum64(v);
    if ((tid & 63) == 0) red[tid >> 6] = v;
    __syncthreads();
    float r = (red[0] + red[1]) + (red[2] + red[3]);
    __syncthreads();
    return r;
}
__device__ __forceinline__ float block_max256(float v, float* red) {
    int tid = threadIdx.x;
    v = wave_max64(v);
    if ((tid & 63) == 0) red[tid >> 6] = v;
    __syncthreads();
    float r = fmaxf(fmaxf(red[0], red[1]), fmaxf(red[2], red[3]));
    __syncthreads();
    return r;
}
__device__ __forceinline__ float gelu_exact(float x) {
    return 0.5f * x * (1.f + erff(x * 0.7071067811865476f));
}
__device__ __forceinline__ float softplus_f(float x) {
    return fmaxf(x, 0.f) + log1pf(expf(-fabsf(x)));
}
__device__ __forceinline__ float silu_f(float x) {
    return x / (1.f + expf(-x));
}

// DPP-based partial-reduce step: v += dpp_mov(v, CTRL) with invalid lanes -> 0.
// After shr1,shr2,shr4,shr8,bcast15,bcast31 the full 64-lane sum is in lane 63.
template<int CTRL>
__device__ __forceinline__ float dpp_add(float v) {
    int t = __builtin_amdgcn_update_dpp(0, __float_as_int(v), CTRL, 0xf, 0xf, true);
    return v + __int_as_float(t);
}

// ---------- bp stage 1: bars @ w1^T + b1 -> LN -> gelu ----------
__global__ __launch_bounds__(256) void bp1_kernel(
    const float* __restrict__ bars, const float* __restrict__ w1,
    const float* __restrict__ b1, const float* __restrict__ g1,
    const float* __restrict__ be1, float* __restrict__ out)
{
    __shared__ float s_in[NF];
    __shared__ float red[4];
    int row = blockIdx.x, tid = threadIdx.x;
    if (tid < NF) s_in[tid] = bars[row * NF + tid];
    __syncthreads();
    float acc = b1[tid];
#pragma unroll
    for (int k = 0; k < NF; k++) acc += s_in[k] * w1[tid * NF + k];
    float mean = block_sum256(acc, red) * (1.f / 256.f);
    float d = acc - mean;
    float var = block_sum256(d * d, red) * (1.f / 256.f);
    float nv = d * rsqrtf(var + 1e-5f) * g1[tid] + be1[tid];
    out[row * 256 + tid] = gelu_exact(nv);
}

// ---------- LN (+mask) ----------
__global__ __launch_bounds__(256) void ln_mask_kernel(
    const float* __restrict__ in, const float* __restrict__ g,
    const float* __restrict__ be, const float* __restrict__ mask,
    float* __restrict__ out)
{
    __shared__ float red[4];
    int row = blockIdx.x, tid = threadIdx.x;
    float v = in[row * 256 + tid];
    float mean = block_sum256(v, red) * (1.f / 256.f);
    float d = v - mean;
    float var = block_sum256(d * d, red) * (1.f / 256.f);
    float nv = d * rsqrtf(var + 1e-5f) * g[tid] + be[tid];
    out[row * 256 + tid] = nv * mask[row];
}

// ---------- LN + residual (X = LN(in)+X) ----------
__global__ __launch_bounds__(256) void ln_res_kernel(
    const float* __restrict__ in, const float* __restrict__ g,
    const float* __restrict__ be, float* __restrict__ X)
{
    __shared__ float red[4];
    int row = blockIdx.x, tid = threadIdx.x;
    float v = in[row * 256 + tid];
    float mean = block_sum256(v, red) * (1.f / 256.f);
    float d = v - mean;
    float var = block_sum256(d * d, red) * (1.f / 256.f);
    float nv = d * rsqrtf(var + 1e-5f) * g[tid] + be[tid];
    X[row * 256 + tid] = nv + X[row * 256 + tid];
}

// ---------- generic tiled GEMM: C[m,n] = sum_k A[m*lda+k]*W[n*K+k] (+bias) ----------
// act: 0 none, 1 softplus
__global__ __launch_bounds__(256) void gemm_nt(
    const float* __restrict__ A, int lda,
    const float* __restrict__ W,
    const float* __restrict__ bias,
    float* __restrict__ C, int ldc,
    int N, int K, int act)
{
    __shared__ float As[64][17];
    __shared__ float Ws[64][17];
    int tid = threadIdx.x;
    int tx = tid & 15, ty = tid >> 4;
    int bm = blockIdx.y * 64, bn = blockIdx.x * 64;
    float acc[4][4] = {};
    for (int kb = 0; kb < K; kb += 16) {
#pragma unroll
        for (int i = 0; i < 4; i++) {
            int idx = i * 256 + tid;
            int r = idx >> 4, kk = idx & 15;
            As[r][kk] = A[(bm + r) * lda + kb + kk];
        }
#pragma unroll
        for (int i = 0; i < 4; i++) {
            int idx = i * 256 + tid;
            int r = idx >> 4, kk = idx & 15;
            int n = bn + r;
            Ws[r][kk] = (n < N) ? W[n * K + kb + kk] : 0.f;
        }
        __syncthreads();
#pragma unroll
        for (int kk = 0; kk < 16; kk++) {
            float a0 = As[ty][kk], a1 = As[ty + 16][kk], a2 = As[ty + 32][kk], a3 = As[ty + 48][kk];
            float w0 = Ws[tx][kk], w1 = Ws[tx + 16][kk], w2 = Ws[tx + 32][kk], w3 = Ws[tx + 48][kk];
            acc[0][0] += a0 * w0; acc[0][1] += a0 * w1; acc[0][2] += a0 * w2; acc[0][3] += a0 * w3;
            acc[1][0] += a1 * w0; acc[1][1] += a1 * w1; acc[1][2] += a1 * w2; acc[1][3] += a1 * w3;
            acc[2][0] += a2 * w0; acc[2][1] += a2 * w1; acc[2][2] += a2 * w2; acc[2][3] += a2 * w3;
            acc[3][0] += a3 * w0; acc[3][1] += a3 * w1; acc[3][2] += a3 * w2; acc[3][3] += a3 * w3;
        }
        __syncthreads();
    }
#pragma unroll
    for (int i = 0; i < 4; i++) {
        int row = bm + ty + i * 16;
#pragma unroll
        for (int j = 0; j < 4; j++) {
            int col = bn + tx + j * 16;
            if (col < N) {
                float v = acc[i][j];
                if (bias) v += bias[col];
                if (act == 1) v = softplus_f(v);
                C[row * ldc + col] = v;
            }
        }
    }
}

// ---------- depthwise causal conv(4) + bias + silu ----------
__global__ __launch_bounds__(256) void conv_silu_kernel(
    const float* __restrict__ XZ, const float* __restrict__ cw,
    const float* __restrict__ cb, float* __restrict__ XC)
{
    int idx = blockIdx.x * 256 + threadIdx.x;   // over kBT*DI
    int d = idx & (DI - 1);
    int bt = idx >> 9;
    int t = bt & (kT - 1);
    float acc = cb[d];
#pragma unroll
    for (int k = 0; k < 4; k++) {
        int tt = t + k - 3;
        if (tt >= 0) acc += XZ[(bt + k - 3) * (2 * DI) + d] * cw[d * 4 + k];
    }
    XC[bt * DI + d] = silu_f(acc);
}

// ---------- selective scan: one wave per (b,d), lane = state ----------
// Chunked (CH timesteps), batched DPP reductions. Zin/Yout are the z-half /
// x-half of the XZ buffer passed as distinct __restrict__ pointers (disjoint
// element sets) so y-stores don't serialize against z-loads.
constexpr int CH = 8;
__global__ __launch_bounds__(256) void scan_kernel(
    const float* __restrict__ DTp, const float* __restrict__ XC,
    const float* __restrict__ DBL, const float* __restrict__ Alog,
    const float* __restrict__ Dp,
    const float* __restrict__ Zin, float* __restrict__ Yout)
{
    int wid = blockIdx.x * 4 + (threadIdx.x >> 6);   // 0..4095
    int lane = threadIdx.x & 63;
    int b = wid >> 9;          // /512
    int d = wid & (DI - 1);
    // a' = A * log2(e) so exp(dt*A) = exp2(dt*a')
    float a2 = -expf(Alog[d * DS + lane]) * 1.4426950408889634f;
    float Dd = Dp[d];
    float h = 0.f;
    int base = b * kT;
    for (int t0 = 0; t0 < kT; t0 += CH) {
        float dtv[CH], xv[CH], zv[CH], Bv[CH], Cv[CH];
#pragma unroll
        for (int j = 0; j < CH; j++) {
            int bt = base + t0 + j;
            dtv[j] = DTp[bt * DI + d];
            xv[j]  = XC[bt * DI + d];
            zv[j]  = Zin[bt * (2 * DI) + d];
            Bv[j]  = DBL[bt * DBLW + DR + lane];
            Cv[j]  = DBL[bt * DBLW + DR + DS + lane];
        }
        float p[CH];
#pragma unroll
        for (int j = 0; j < CH; j++) {
            float dA = exp2f(dtv[j] * a2);
            h = dA * h + (dtv[j] * xv[j]) * Bv[j];
            p[j] = h * Cv[j];
        }
        // batched wave64 sum: 6 DPP levels, 8 independent values per level
#pragma unroll
        for (int j = 0; j < CH; j++) p[j] = dpp_add<0x111>(p[j]); // row_shr:1
#pragma unroll
        for (int j = 0; j < CH; j++) p[j] = dpp_add<0x112>(p[j]); // row_shr:2
#pragma unroll
        for (int j = 0; j < CH; j++) p[j] = dpp_add<0x114>(p[j]); // row_shr:4
#pragma unroll
        for (int j = 0; j < CH; j++) p[j] = dpp_add<0x118>(p[j]); // row_shr:8
#pragma unroll
        for (int j = 0; j < CH; j++) p[j] = dpp_add<0x142>(p[j]); // row_bcast:15
#pragma unroll
        for (int j = 0; j < CH; j++) p[j] = dpp_add<0x143>(p[j]); // row_bcast:31
        // lane 63 now holds the full sum for each j
#pragma unroll
        for (int j = 0; j < CH; j++) {
            float z = zv[j];
            float y = (p[j] + xv[j] * Dd) * (z / (1.f + __expf(-z)));
            if (lane == 63) Yout[(base + t0 + j) * (2 * DI) + d] = y;
        }
    }
}

// ---------- pooling ----------
__global__ __launch_bounds__(256) void pool_logits_kernel(
    const float* __restrict__ X, const float* __restrict__ pw,
    const float* __restrict__ pb, float* __restrict__ LG)
{
    int wid = blockIdx.x * 4 + (threadIdx.x >> 6);  // row in [0,kBT)
    int lane = threadIdx.x & 63;
    float acc = 0.f;
#pragma unroll
    for (int c = 0; c < 4; c++) {
        int k = lane + 64 * c;
        acc += X[(size_t)wid * 256 + k] * pw[k];
    }
    acc = wave_sum64(acc);
    if (lane == 0) LG[wid] = acc + pb[0];
}

__global__ __launch_bounds__(256) void softmax_T_kernel(float* __restrict__ LG)
{
    __shared__ float red[4];
    int b = blockIdx.x, tid = threadIdx.x;
    float l[8];
    float m = -1e30f;
#pragma unroll
    for (int c = 0; c < 8; c++) {
        l[c] = LG[b * kT + tid + 256 * c];
        m = fmaxf(m, l[c]);
    }
    m = block_max256(m, red);
    float s = 0.f;
#pragma unroll
    for (int c = 0; c < 8; c++) { l[c] = expf(l[c] - m); s += l[c]; }
    s = block_sum256(s, red);
    float inv = 1.f / s;
#pragma unroll
    for (int c = 0; c < 8; c++) LG[b * kT + tid + 256 * c] = l[c] * inv;
}

__global__ __launch_bounds__(1024) void hp_kernel(
    const float* __restrict__ WTS, const float* __restrict__ X,
    float* __restrict__ HP)
{
    __shared__ float part[4][256];
    int b = blockIdx.x;
    int n = threadIdx.x & 255, c = threadIdx.x >> 8;
    float acc = 0.f;
    int t0 = c * 512;
    for (int t = t0; t < t0 + 512; t++) {
        int bt = b * kT + t;
        acc += WTS[bt] * X[(size_t)bt * 256 + n];
    }
    part[c][n] = acc;
    __syncthreads();
    if (c == 0) HP[b * 256 + n] = part[0][n] + part[1][n] + part[2][n] + part[3][n];
}

// ---------- heads (128 threads / block, 1 block per batch) ----------
__device__ __forceinline__ float ln128_gelu(float v, const float* g, const float* be, float* red)
{
    int tid = threadIdx.x;
    red[tid] = v; __syncthreads();
#pragma unroll
    for (int s = 64; s > 0; s >>= 1) { if (tid < s) red[tid] += red[tid + s]; __syncthreads(); }
    float mean = red[0] * (1.f / 128.f); __syncthreads();
    float d = v - mean;
    red[tid] = d * d; __syncthreads();
#pragma unroll
    for (int s = 64; s > 0; s >>= 1) { if (tid < s) red[tid] += red[tid + s]; __syncthreads(); }
    float var = red[0] * (1.f / 128.f); __syncthreads();
    float nv = d * rsqrtf(var + 1e-5f) * g[tid] + be[tid];
    return gelu_exact(nv);
}

__global__ __launch_bounds__(128) void head_kernel(
    const float* __restrict__ HP,
    const float* __restrict__ h_w1, const float* __restrict__ h_b1,
    const float* __restrict__ h_g1, const float* __restrict__ h_be1,
    const float* __restrict__ h_w2, const float* __restrict__ h_b2,
    const float* __restrict__ h_g2, const float* __restrict__ h_be2,
    const float* __restrict__ h_w3, const float* __restrict__ h_b3,
    const float* __restrict__ c_w1, const float* __restrict__ c_b1,
    const float* __restrict__ c_g1, const float* __restrict__ c_be1,
    const float* __restrict__ c_w2, const float* __restrict__ c_b2,
    float* __restrict__ out)
{
    __shared__ float s_hp[256];
    __shared__ float s1[128];
    __shared__ float red[128];
    int b = blockIdx.x, tid = threadIdx.x;
    s_hp[tid] = HP[b * 256 + tid];
    s_hp[tid + 128] = HP[b * 256 + tid + 128];
    __syncthreads();

    // h branch layer 1
    float v = h_b1[tid];
    for (int k = 0; k < 256; k++) v += s_hp[k] * h_w1[tid * 256 + k];
    float g1v = ln128_gelu(v, h_g1, h_be1, red);
    s1[tid] = g1v;
    __syncthreads();

    // h branch layer 2
    float v2 = h_b2[tid];
    for (int k = 0; k < 128; k++) v2 += s1[k] * h_w2[tid * 128 + k];
    float g2v = ln128_gelu(v2, h_g2, h_be2, red);

    // vix = dot(g2v, h_w3) + b3
    red[tid] = g2v * h_w3[tid];
    __syncthreads();
#pragma unroll
    for (int s = 64; s > 0; s >>= 1) { if (tid < s) red[tid] += red[tid + s]; __syncthreads(); }
    if (tid == 0) out[b] = red[0] + h_b3[0];
    __syncthreads();

    // c branch
    float vc = c_b1[tid];
    for (int k = 0; k < 256; k++) vc += s_hp[k] * c_w1[tid * 256 + k];
    float gcv = ln128_gelu(vc, c_g1, c_be1, red);
    s1[tid] = gcv;
    __syncthreads();
    if (tid < NBUCK) {
        float acc = c_b2[tid];
        for (int k = 0; k < 128; k++) acc += s1[k] * c_w2[tid * 128 + k];
        out[8 + b * NBUCK + tid] = acc;
    }
}

// ---------- launch ----------
extern "C" void kernel_launch(void* const* d_in, const int* in_sizes, int n_in,
                              void* d_out, int out_size, void* d_ws, size_t ws_size,
                              hipStream_t stream)
{
    const float* bars     = (const float*)d_in[0];
    const float* bar_mask = (const float*)d_in[1];
    const float* bp_w1    = (const float*)d_in[2];
    const float* bp_b1    = (const float*)d_in[3];
    const float* bp_g1    = (const float*)d_in[4];
    const float* bp_be1   = (const float*)d_in[5];
    const float* bp_w2    = (const float*)d_in[6];
    const float* bp_b2    = (const float*)d_in[7];
    const float* bp_g2    = (const float*)d_in[8];
    const float* bp_be2   = (const float*)d_in[9];
    const float* m_in_w   = (const float*)d_in[10];
    const float* m_conv_w = (const float*)d_in[11];
    const float* m_conv_b = (const float*)d_in[12];
    const float* m_xproj_w= (const float*)d_in[13];
    const float* m_dt_w   = (const float*)d_in[14];
    const float* m_dt_b   = (const float*)d_in[15];
    const float* m_Alog   = (const float*)d_in[16];
    const float* m_D      = (const float*)d_in[17];
    const float* m_out_w  = (const float*)d_in[18];
    const float* m_ln_g   = (const float*)d_in[19];
    const float* m_ln_b   = (const float*)d_in[20];
    const float* pool_w   = (const float*)d_in[21];
    const float* pool_b   = (const float*)d_in[22];
    const float* h_w1     = (const float*)d_in[23];
    const float* h_b1     = (const float*)d_in[24];
    const float* h_g1     = (const float*)d_in[25];
    const float* h_be1    = (const float*)d_in[26];
    const float* h_w2     = (const float*)d_in[27];
    const float* h_b2     = (const float*)d_in[28];
    const float* h_g2     = (const float*)d_in[29];
    const float* h_be2    = (const float*)d_in[30];
    const float* h_w3     = (const float*)d_in[31];
    const float* h_b3     = (const float*)d_in[32];
    const float* c_w1     = (const float*)d_in[33];
    const float* c_b1     = (const float*)d_in[34];
    const float* c_g1     = (const float*)d_in[35];
    const float* c_be1    = (const float*)d_in[36];
    const float* c_w2     = (const float*)d_in[37];
    const float* c_b2     = (const float*)d_in[38];
    float* out = (float*)d_out;

    float* ws = (float*)d_ws;
    float* X   = ws;                       // kBT*256
    float* XZ  = X   + (size_t)kBT * 256;  // kBT*1024
    float* XC  = XZ  + (size_t)kBT * 1024; // kBT*512
    float* DBL = XC  + (size_t)kBT * 512;  // kBT*144
    float* DTb = DBL + (size_t)kBT * DBLW; // kBT*512
    float* OUT = DTb + (size_t)kBT * 512;  // kBT*256
    float* LG  = OUT + (size_t)kBT * 256;  // kBT
    float* HP  = LG  + (size_t)kBT;        // kB*256

    // bar projection
    bp1_kernel<<<kBT, 256, 0, stream>>>(bars, bp_w1, bp_b1, bp_g1, bp_be1, OUT);
    gemm_nt<<<dim3(4, kBT / 64), 256, 0, stream>>>(OUT, 256, bp_w2, bp_b2, XC, 256, 256, 256, 0);
    ln_mask_kernel<<<kBT, 256, 0, stream>>>(XC, bp_g2, bp_be2, bar_mask, X);

    for (int i = 0; i < NLAY; i++) {
        const float* in_w  = m_in_w   + (size_t)i * 2 * DI * DM;
        const float* cw    = m_conv_w + (size_t)i * DI * 4;
        const float* cb    = m_conv_b + (size_t)i * DI;
        const float* xpw   = m_xproj_w+ (size_t)i * DBLW * DI;
        const float* dtw   = m_dt_w   + (size_t)i * DI * DR;
        const float* dtb   = m_dt_b   + (size_t)i * DI;
        const float* alog  = m_Alog   + (size_t)i * DI * DS;
        const float* dp    = m_D      + (size_t)i * DI;
        const float* outw  = m_out_w  + (size_t)i * DM * DI;
        const float* lng   = m_ln_g   + (size_t)i * DM;
        const float* lnb   = m_ln_b   + (size_t)i * DM;

        // xz = x @ in_w^T   (N=1024, K=256)
        gemm_nt<<<dim3(16, kBT / 64), 256, 0, stream>>>(X, 256, in_w, nullptr, XZ, 1024, 1024, 256, 0);
        // depthwise conv + silu -> XC
        conv_silu_kernel<<<(kBT * DI) / 256, 256, 0, stream>>>(XZ, cw, cb, XC);
        // dbl = XC @ xproj^T (N=144, K=512)
        gemm_nt<<<dim3(3, kBT / 64), 256, 0, stream>>>(XC, 512, xpw, nullptr, DBL, DBLW, DBLW, 512, 0);
        // dt = softplus(dbl[:, :16] @ dt_w^T + dt_b) (N=512, K=16)
        gemm_nt<<<dim3(8, kBT / 64), 256, 0, stream>>>(DBL, DBLW, dtw, dtb, DTb, 512, 512, 16, 1);
        // selective scan + gating, writes gated y into XZ[:, :512]
        scan_kernel<<<1024, 256, 0, stream>>>(DTb, XC, DBL, alog, dp, XZ + DI, XZ);
        // out = y @ out_w^T (N=256, K=512)
        gemm_nt<<<dim3(4, kBT / 64), 256, 0, stream>>>(XZ, 1024, outw, nullptr, OUT, 256, 256, 512, 0);
        // x = LN(out) + x
        ln_res_kernel<<<kBT, 256, 0, stream>>>(OUT, lng, lnb, X);
    }

    // pooling
    pool_logits_kernel<<<kBT / 4, 256, 0, stream>>>(X, pool_w, pool_b, LG);
    softmax_T_kernel<<<kB, 256, 0, stream>>>(LG);
    hp_kernel<<<kB, 1024, 0, stream>>>(LG, X, HP);

    // heads
    head_kernel<<<kB, 128, 0, stream>>>(HP,
        h_w1, h_b1, h_g1, h_be1, h_w2, h_b2, h_g2, h_be2, h_w3, h_b3,
        c_w1, c_b1, c_g1, c_be1, c_w2, c_b2, out);
}

// Round 3
// 4520.130 us; speedup vs baseline: 2.0118x; 1.1203x over previous
//
#include <hip/hip_runtime.h>
#include <math.h>

// ---- problem constants ----
constexpr int kB   = 8;
constexpr int kT   = 2048;
constexpr int kBT  = kB * kT;      // 16384
constexpr int DM   = 256;          // d_model
constexpr int DI   = 512;          // d_inner
constexpr int DS   = 64;           // d_state
constexpr int DR   = 16;           // dt_rank
constexpr int NF   = 15;           // nfeat
constexpr int HID  = 128;
constexpr int NBUCK= 15;
constexpr int NLAY = 4;
constexpr int DBLW = DR + 2*DS;    // 144

// ---------- helpers ----------
__device__ __forceinline__ float wave_sum64(float v) {
#pragma unroll
    for (int off = 32; off > 0; off >>= 1) v += __shfl_xor(v, off, 64);
    return v;
}
__device__ __forceinline__ float wave_max64(float v) {
#pragma unroll
    for (int off = 32; off > 0; off >>= 1) v = fmaxf(v, __shfl_xor(v, off, 64));
    return v;
}
__device__ __forceinline__ float block_sum256(float v, float* red) {
    int tid = threadIdx.x;
    v = wave_sum64(v);
    if ((tid & 63) == 0) red[tid >> 6] = v;
    __syncthreads();
    float r = (red[0] + red[1]) + (red[2] + red[3]);
    __syncthreads();
    return r;
}
__device__ __forceinline__ float block_max256(float v, float* red) {
    int tid = threadIdx.x;
    v = wave_max64(v);
    if ((tid & 63) == 0) red[tid >> 6] = v;
    __syncthreads();
    float r = fmaxf(fmaxf(red[0], red[1]), fmaxf(red[2], red[3]));
    __syncthreads();
    return r;
}
__device__ __forceinline__ float gelu_exact(float x) {
    return 0.5f * x * (1.f + erff(x * 0.7071067811865476f));
}
__device__ __forceinline__ float softplus_f(float x) {
    return fmaxf(x, 0.f) + log1pf(expf(-fabsf(x)));
}
__device__ __forceinline__ float silu_f(float x) {
    return x / (1.f + expf(-x));
}

// DPP add: v += dpp_mov(v, CTRL). row_ror:N (CTRL=0x120+N) gives cyclic
// rotation within each row of 16 -> 4 levels yield full row sum in ALL lanes.
template<int CTRL>
__device__ __forceinline__ float dpp_add(float v) {
    int t = __builtin_amdgcn_update_dpp(0, __float_as_int(v), CTRL, 0xf, 0xf, true);
    return v + __int_as_float(t);
}

// ---------- bp stage 1: bars @ w1^T + b1 -> LN -> gelu ----------
__global__ __launch_bounds__(256) void bp1_kernel(
    const float* __restrict__ bars, const float* __restrict__ w1,
    const float* __restrict__ b1, const float* __restrict__ g1,
    const float* __restrict__ be1, float* __restrict__ out)
{
    __shared__ float s_in[NF];
    __shared__ float red[4];
    int row = blockIdx.x, tid = threadIdx.x;
    if (tid < NF) s_in[tid] = bars[row * NF + tid];
    __syncthreads();
    float acc = b1[tid];
#pragma unroll
    for (int k = 0; k < NF; k++) acc += s_in[k] * w1[tid * NF + k];
    float mean = block_sum256(acc, red) * (1.f / 256.f);
    float d = acc - mean;
    float var = block_sum256(d * d, red) * (1.f / 256.f);
    float nv = d * rsqrtf(var + 1e-5f) * g1[tid] + be1[tid];
    out[row * 256 + tid] = gelu_exact(nv);
}

// ---------- LN (+mask) ----------
__global__ __launch_bounds__(256) void ln_mask_kernel(
    const float* __restrict__ in, const float* __restrict__ g,
    const float* __restrict__ be, const float* __restrict__ mask,
    float* __restrict__ out)
{
    __shared__ float red[4];
    int row = blockIdx.x, tid = threadIdx.x;
    float v = in[row * 256 + tid];
    float mean = block_sum256(v, red) * (1.f / 256.f);
    float d = v - mean;
    float var = block_sum256(d * d, red) * (1.f / 256.f);
    float nv = d * rsqrtf(var + 1e-5f) * g[tid] + be[tid];
    out[row * 256 + tid] = nv * mask[row];
}

// ---------- LN + residual (X = LN(in)+X) ----------
__global__ __launch_bounds__(256) void ln_res_kernel(
    const float* __restrict__ in, const float* __restrict__ g,
    const float* __restrict__ be, float* __restrict__ X)
{
    __shared__ float red[4];
    int row = blockIdx.x, tid = threadIdx.x;
    float v = in[row * 256 + tid];
    float mean = block_sum256(v, red) * (1.f / 256.f);
    float d = v - mean;
    float var = block_sum256(d * d, red) * (1.f / 256.f);
    float nv = d * rsqrtf(var + 1e-5f) * g[tid] + be[tid];
    X[row * 256 + tid] = nv + X[row * 256 + tid];
}

// ---------- tiled GEMM with optional transposed A (A stored [K][M]) and
// transposed C store (C stored [N][M]). A normal: C[m,n]=sum_k A[m*lda+k]W[n*K+k].
// act: 0 none, 1 softplus ----------
__global__ __launch_bounds__(256) void gemm_nt(
    const float* __restrict__ A, int lda,
    const float* __restrict__ W,
    const float* __restrict__ bias,
    float* __restrict__ C, int ldc,
    int N, int K, int act, int transA, int transC)
{
    __shared__ float As[64][17];
    __shared__ float Ws[64][17];
    int tid = threadIdx.x;
    int tx = tid & 15, ty = tid >> 4;
    int bm = blockIdx.y * 64, bn = blockIdx.x * 64;
    float acc[4][4] = {};
    for (int kb = 0; kb < K; kb += 16) {
        if (transA) {
#pragma unroll
            for (int i = 0; i < 4; i++) {
                int idx = i * 256 + tid;
                int r = idx & 63, kk = idx >> 6;   // coalesced along r
                As[r][kk] = A[(kb + kk) * (size_t)lda + bm + r];
            }
        } else {
#pragma unroll
            for (int i = 0; i < 4; i++) {
                int idx = i * 256 + tid;
                int r = idx >> 4, kk = idx & 15;
                As[r][kk] = A[(bm + r) * (size_t)lda + kb + kk];
            }
        }
#pragma unroll
        for (int i = 0; i < 4; i++) {
            int idx = i * 256 + tid;
            int r = idx >> 4, kk = idx & 15;
            int n = bn + r;
            Ws[r][kk] = (n < N) ? W[n * (size_t)K + kb + kk] : 0.f;
        }
        __syncthreads();
#pragma unroll
        for (int kk = 0; kk < 16; kk++) {
            float a0 = As[ty][kk], a1 = As[ty + 16][kk], a2 = As[ty + 32][kk], a3 = As[ty + 48][kk];
            float w0 = Ws[tx][kk], w1 = Ws[tx + 16][kk], w2 = Ws[tx + 32][kk], w3 = Ws[tx + 48][kk];
            acc[0][0] += a0 * w0; acc[0][1] += a0 * w1; acc[0][2] += a0 * w2; acc[0][3] += a0 * w3;
            acc[1][0] += a1 * w0; acc[1][1] += a1 * w1; acc[1][2] += a1 * w2; acc[1][3] += a1 * w3;
            acc[2][0] += a2 * w0; acc[2][1] += a2 * w1; acc[2][2] += a2 * w2; acc[2][3] += a2 * w3;
            acc[3][0] += a3 * w0; acc[3][1] += a3 * w1; acc[3][2] += a3 * w2; acc[3][3] += a3 * w3;
        }
        __syncthreads();
    }
#pragma unroll
    for (int i = 0; i < 4; i++) {
        int row = bm + ty + i * 16;
#pragma unroll
        for (int j = 0; j < 4; j++) {
            int col = bn + tx + j * 16;
            if (col < N) {
                float v = acc[i][j];
                if (bias) v += bias[col];
                if (act == 1) v = softplus_f(v);
                if (transC) C[(size_t)col * ldc + row] = v;
                else        C[(size_t)row * ldc + col] = v;
            }
        }
    }
}

// ---------- depthwise causal conv(4) + bias + silu, [d][bt] layout ----------
__global__ __launch_bounds__(256) void conv_silu_kernel(
    const float* __restrict__ XT, const float* __restrict__ cw,
    const float* __restrict__ cb, float* __restrict__ XCt)
{
    int idx = blockIdx.x * 256 + threadIdx.x;   // d*kBT + bt
    int bt = idx & (kBT - 1);
    int d  = idx >> 14;
    int t  = bt & (kT - 1);
    float acc = cb[d];
    const float* xr = XT + (size_t)d * kBT + bt;
#pragma unroll
    for (int k = 0; k < 4; k++) {
        int tt = t + k - 3;
        if (tt >= 0) acc += xr[k - 3] * cw[d * 4 + k];
    }
    XCt[idx] = silu_f(acc);
}

// ---------- selective scan: one wave per (b,d), lane = state ----------
// All operands in [channel][b][t] layout. dt/x/z wave-uniform float4 loads;
// B/C one dwordx4 pair per lane per chunk; ror-DPP + shfl_xor butterfly
// reduce (result uniform in all lanes); distributed epilogue (lane j = step j);
// software-pipelined chunk preload.
constexpr int CH = 8;
__global__ __launch_bounds__(256) void scan_kernel(
    const float* __restrict__ DTt, const float* __restrict__ XCt,
    const float* __restrict__ DBLt, const float* __restrict__ Alog,
    const float* __restrict__ Dp,
    const float* __restrict__ ZT, float* __restrict__ Yt)
{
    int wid = blockIdx.x * 4 + (threadIdx.x >> 6);   // 0..4095
    int lane = threadIdx.x & 63;
    int b = wid >> 9;          // /512
    int d = wid & (DI - 1);
    float a2 = -expf(Alog[d * DS + lane]) * 1.4426950408889634f;
    float Dd = Dp[d];
    unsigned off = (unsigned)__builtin_amdgcn_readfirstlane(d * kBT + b * kT);
    const float* dtp = DTt + off;
    const float* xp  = XCt + off;
    const float* Bp  = DBLt + (size_t)(DR + lane) * kBT + b * kT;
    const float* Cp  = DBLt + (size_t)(DR + DS + lane) * kBT + b * kT;
    const float* xq  = xp + (lane & 7);
    const float* zq  = ZT + off + (lane & 7);
    float* yq = Yt + off + lane;   // lanes 0-7 store
    bool b0 = (lane & 1) != 0, b1 = (lane & 2) != 0, b2 = (lane & 4) != 0;
    float h = 0.f;

    float4 dta = *(const float4*)(dtp),     dtb = *(const float4*)(dtp + 4);
    float4 xa  = *(const float4*)(xp),      xb  = *(const float4*)(xp + 4);
    float4 Ba  = *(const float4*)(Bp),      Bb  = *(const float4*)(Bp + 4);
    float4 Ca  = *(const float4*)(Cp),      Cb  = *(const float4*)(Cp + 4);
    float  zP  = zq[0], xP = xq[0];

    for (int t0 = 0; t0 < kT; t0 += CH) {
        int t1 = (t0 + CH < kT) ? (t0 + CH) : t0;   // clamp: last iter reloads
        float4 ndta = *(const float4*)(dtp + t1), ndtb = *(const float4*)(dtp + t1 + 4);
        float4 nxa  = *(const float4*)(xp + t1),  nxb  = *(const float4*)(xp + t1 + 4);
        float4 nBa  = *(const float4*)(Bp + t1),  nBb  = *(const float4*)(Bp + t1 + 4);
        float4 nCa  = *(const float4*)(Cp + t1),  nCb  = *(const float4*)(Cp + t1 + 4);
        float  nzP  = zq[t1], nxP = xq[t1];

        float dts[8] = {dta.x, dta.y, dta.z, dta.w, dtb.x, dtb.y, dtb.z, dtb.w};
        float xs[8]  = {xa.x,  xa.y,  xa.z,  xa.w,  xb.x,  xb.y,  xb.z,  xb.w};
        float Bs[8]  = {Ba.x,  Ba.y,  Ba.z,  Ba.w,  Bb.x,  Bb.y,  Bb.z,  Bb.w};
        float Cs[8]  = {Ca.x,  Ca.y,  Ca.z,  Ca.w,  Cb.x,  Cb.y,  Cb.z,  Cb.w};
        float p[8];
#pragma unroll
        for (int j = 0; j < 8; j++) {
            float dA = exp2f(dts[j] * a2);
            h = fmaf(dA, h, (dts[j] * xs[j]) * Bs[j]);
            p[j] = h * Cs[j];
        }
#pragma unroll
        for (int j = 0; j < 8; j++) p[j] = dpp_add<0x121>(p[j]); // row_ror:1
#pragma unroll
        for (int j = 0; j < 8; j++) p[j] = dpp_add<0x122>(p[j]); // row_ror:2
#pragma unroll
        for (int j = 0; j < 8; j++) p[j] = dpp_add<0x124>(p[j]); // row_ror:4
#pragma unroll
        for (int j = 0; j < 8; j++) p[j] = dpp_add<0x128>(p[j]); // row_ror:8
#pragma unroll
        for (int j = 0; j < 8; j++) p[j] += __shfl_xor(p[j], 16, 64);
#pragma unroll
        for (int j = 0; j < 8; j++) p[j] += __shfl_xor(p[j], 32, 64);
        // gather: lane l takes p[l&7]
        float m01 = b0 ? p[1] : p[0];
        float m23 = b0 ? p[3] : p[2];
        float m45 = b0 ? p[5] : p[4];
        float m67 = b0 ? p[7] : p[6];
        float m0123 = b1 ? m23 : m01;
        float m4567 = b1 ? m67 : m45;
        float pP = b2 ? m4567 : m0123;
        float y = fmaf(xP, Dd, pP) * (zP / (1.f + __expf(-zP)));
        if (lane < 8) yq[t0] = y;

        dta = ndta; dtb = ndtb; xa = nxa; xb = nxb;
        Ba = nBa; Bb = nBb; Ca = nCa; Cb = nCb; zP = nzP; xP = nxP;
    }
}

// ---------- pooling ----------
__global__ __launch_bounds__(256) void pool_logits_kernel(
    const float* __restrict__ X, const float* __restrict__ pw,
    const float* __restrict__ pb, float* __restrict__ LG)
{
    int wid = blockIdx.x * 4 + (threadIdx.x >> 6);  // row in [0,kBT)
    int lane = threadIdx.x & 63;
    float acc = 0.f;
#pragma unroll
    for (int c = 0; c < 4; c++) {
        int k = lane + 64 * c;
        acc += X[(size_t)wid * 256 + k] * pw[k];
    }
    acc = wave_sum64(acc);
    if (lane == 0) LG[wid] = acc + pb[0];
}

__global__ __launch_bounds__(256) void softmax_T_kernel(float* __restrict__ LG)
{
    __shared__ float red[4];
    int b = blockIdx.x, tid = threadIdx.x;
    float l[8];
    float m = -1e30f;
#pragma unroll
    for (int c = 0; c < 8; c++) {
        l[c] = LG[b * kT + tid + 256 * c];
        m = fmaxf(m, l[c]);
    }
    m = block_max256(m, red);
    float s = 0.f;
#pragma unroll
    for (int c = 0; c < 8; c++) { l[c] = expf(l[c] - m); s += l[c]; }
    s = block_sum256(s, red);
    float inv = 1.f / s;
#pragma unroll
    for (int c = 0; c < 8; c++) LG[b * kT + tid + 256 * c] = l[c] * inv;
}

__global__ __launch_bounds__(1024) void hp_kernel(
    const float* __restrict__ WTS, const float* __restrict__ X,
    float* __restrict__ HP)
{
    __shared__ float part[4][256];
    int b = blockIdx.x;
    int n = threadIdx.x & 255, c = threadIdx.x >> 8;
    float acc = 0.f;
    int t0 = c * 512;
    for (int t = t0; t < t0 + 512; t++) {
        int bt = b * kT + t;
        acc += WTS[bt] * X[(size_t)bt * 256 + n];
    }
    part[c][n] = acc;
    __syncthreads();
    if (c == 0) HP[b * 256 + n] = part[0][n] + part[1][n] + part[2][n] + part[3][n];
}

// ---------- heads (128 threads / block, 1 block per batch) ----------
__device__ __forceinline__ float ln128_gelu(float v, const float* g, const float* be, float* red)
{
    int tid = threadIdx.x;
    red[tid] = v; __syncthreads();
#pragma unroll
    for (int s = 64; s > 0; s >>= 1) { if (tid < s) red[tid] += red[tid + s]; __syncthreads(); }
    float mean = red[0] * (1.f / 128.f); __syncthreads();
    float d = v - mean;
    red[tid] = d * d; __syncthreads();
#pragma unroll
    for (int s = 64; s > 0; s >>= 1) { if (tid < s) red[tid] += red[tid + s]; __syncthreads(); }
    float var = red[0] * (1.f / 128.f); __syncthreads();
    float nv = d * rsqrtf(var + 1e-5f) * g[tid] + be[tid];
    return gelu_exact(nv);
}

__global__ __launch_bounds__(128) void head_kernel(
    const float* __restrict__ HP,
    const float* __restrict__ h_w1, const float* __restrict__ h_b1,
    const float* __restrict__ h_g1, const float* __restrict__ h_be1,
    const float* __restrict__ h_w2, const float* __restrict__ h_b2,
    const float* __restrict__ h_g2, const float* __restrict__ h_be2,
    const float* __restrict__ h_w3, const float* __restrict__ h_b3,
    const float* __restrict__ c_w1, const float* __restrict__ c_b1,
    const float* __restrict__ c_g1, const float* __restrict__ c_be1,
    const float* __restrict__ c_w2, const float* __restrict__ c_b2,
    float* __restrict__ out)
{
    __shared__ float s_hp[256];
    __shared__ float s1[128];
    __shared__ float red[128];
    int b = blockIdx.x, tid = threadIdx.x;
    s_hp[tid] = HP[b * 256 + tid];
    s_hp[tid + 128] = HP[b * 256 + tid + 128];
    __syncthreads();

    float v = h_b1[tid];
    for (int k = 0; k < 256; k++) v += s_hp[k] * h_w1[tid * 256 + k];
    float g1v = ln128_gelu(v, h_g1, h_be1, red);
    s1[tid] = g1v;
    __syncthreads();

    float v2 = h_b2[tid];
    for (int k = 0; k < 128; k++) v2 += s1[k] * h_w2[tid * 128 + k];
    float g2v = ln128_gelu(v2, h_g2, h_be2, red);

    red[tid] = g2v * h_w3[tid];
    __syncthreads();
#pragma unroll
    for (int s = 64; s > 0; s >>= 1) { if (tid < s) red[tid] += red[tid + s]; __syncthreads(); }
    if (tid == 0) out[b] = red[0] + h_b3[0];
    __syncthreads();

    float vc = c_b1[tid];
    for (int k = 0; k < 256; k++) vc += s_hp[k] * c_w1[tid * 256 + k];
    float gcv = ln128_gelu(vc, c_g1, c_be1, red);
    s1[tid] = gcv;
    __syncthreads();
    if (tid < NBUCK) {
        float acc = c_b2[tid];
        for (int k = 0; k < 128; k++) acc += s1[k] * c_w2[tid * 128 + k];
        out[8 + b * NBUCK + tid] = acc;
    }
}

// ---------- launch ----------
extern "C" void kernel_launch(void* const* d_in, const int* in_sizes, int n_in,
                              void* d_out, int out_size, void* d_ws, size_t ws_size,
                              hipStream_t stream)
{
    const float* bars     = (const float*)d_in[0];
    const float* bar_mask = (const float*)d_in[1];
    const float* bp_w1    = (const float*)d_in[2];
    const float* bp_b1    = (const float*)d_in[3];
    const float* bp_g1    = (const float*)d_in[4];
    const float* bp_be1   = (const float*)d_in[5];
    const float* bp_w2    = (const float*)d_in[6];
    const float* bp_b2    = (const float*)d_in[7];
    const float* bp_g2    = (const float*)d_in[8];
    const float* bp_be2   = (const float*)d_in[9];
    const float* m_in_w   = (const float*)d_in[10];
    const float* m_conv_w = (const float*)d_in[11];
    const float* m_conv_b = (const float*)d_in[12];
    const float* m_xproj_w= (const float*)d_in[13];
    const float* m_dt_w   = (const float*)d_in[14];
    const float* m_dt_b   = (const float*)d_in[15];
    const float* m_Alog   = (const float*)d_in[16];
    const float* m_D      = (const float*)d_in[17];
    const float* m_out_w  = (const float*)d_in[18];
    const float* m_ln_g   = (const float*)d_in[19];
    const float* m_ln_b   = (const float*)d_in[20];
    const float* pool_w   = (const float*)d_in[21];
    const float* pool_b   = (const float*)d_in[22];
    const float* h_w1     = (const float*)d_in[23];
    const float* h_b1     = (const float*)d_in[24];
    const float* h_g1     = (const float*)d_in[25];
    const float* h_be1    = (const float*)d_in[26];
    const float* h_w2     = (const float*)d_in[27];
    const float* h_b2     = (const float*)d_in[28];
    const float* h_g2     = (const float*)d_in[29];
    const float* h_be2    = (const float*)d_in[30];
    const float* h_w3     = (const float*)d_in[31];
    const float* h_b3     = (const float*)d_in[32];
    const float* c_w1     = (const float*)d_in[33];
    const float* c_b1     = (const float*)d_in[34];
    const float* c_g1     = (const float*)d_in[35];
    const float* c_be1    = (const float*)d_in[36];
    const float* c_w2     = (const float*)d_in[37];
    const float* c_b2     = (const float*)d_in[38];
    float* out = (float*)d_out;

    float* ws = (float*)d_ws;
    float* X    = ws;                         // kBT*256
    float* XZt  = X    + (size_t)kBT * 256;   // [1024][kBT]  (rows 0-511: x / y; 512-1023: z)
    float* XCt  = XZt  + (size_t)1024 * kBT;  // [512][kBT]
    float* DBLt = XCt  + (size_t)512 * kBT;   // [144][kBT]
    float* DTt  = DBLt + (size_t)DBLW * kBT;  // [512][kBT]  (also bp scratch)
    float* OUT  = DTt  + (size_t)512 * kBT;   // kBT*256
    float* LG   = OUT  + (size_t)kBT * 256;   // kBT
    float* HP   = LG   + (size_t)kBT;         // kB*256

    // bar projection
    bp1_kernel<<<kBT, 256, 0, stream>>>(bars, bp_w1, bp_b1, bp_g1, bp_be1, OUT);
    gemm_nt<<<dim3(4, kBT / 64), 256, 0, stream>>>(OUT, 256, bp_w2, bp_b2, DTt, 256, 256, 256, 0, 0, 0);
    ln_mask_kernel<<<kBT, 256, 0, stream>>>(DTt, bp_g2, bp_be2, bar_mask, X);

    for (int i = 0; i < NLAY; i++) {
        const float* in_w  = m_in_w   + (size_t)i * 2 * DI * DM;
        const float* cw    = m_conv_w + (size_t)i * DI * 4;
        const float* cb    = m_conv_b + (size_t)i * DI;
        const float* xpw   = m_xproj_w+ (size_t)i * DBLW * DI;
        const float* dtw   = m_dt_w   + (size_t)i * DI * DR;
        const float* dtb   = m_dt_b   + (size_t)i * DI;
        const float* alog  = m_Alog   + (size_t)i * DI * DS;
        const float* dp    = m_D      + (size_t)i * DI;
        const float* outw  = m_out_w  + (size_t)i * DM * DI;
        const float* lng   = m_ln_g   + (size_t)i * DM;
        const float* lnb   = m_ln_b   + (size_t)i * DM;

        // xz^T = (x @ in_w^T)^T  -> XZt [1024][kBT]
        gemm_nt<<<dim3(16, kBT / 64), 256, 0, stream>>>(X, 256, in_w, nullptr, XZt, kBT, 1024, 256, 0, 0, 1);
        // depthwise conv + silu on [d][bt]
        conv_silu_kernel<<<(kBT * DI) / 256, 256, 0, stream>>>(XZt, cw, cb, XCt);
        // dbl^T = (xc @ xproj^T)^T -> DBLt [144][kBT]   (A transposed)
        gemm_nt<<<dim3(3, kBT / 64), 256, 0, stream>>>(XCt, kBT, xpw, nullptr, DBLt, kBT, DBLW, 512, 0, 1, 1);
        // dt^T = softplus(dbl[:, :16] @ dt_w^T + dt_b)^T -> DTt [512][kBT]
        gemm_nt<<<dim3(8, kBT / 64), 256, 0, stream>>>(DBLt, kBT, dtw, dtb, DTt, kBT, 512, 16, 1, 1, 1);
        // selective scan + gating; writes y^T into XZt rows 0-511
        scan_kernel<<<1024, 256, 0, stream>>>(DTt, XCt, DBLt, alog, dp, XZt + (size_t)DI * kBT, XZt);
        // out = y @ out_w^T (A = Yt transposed) -> OUT [bt][256]
        gemm_nt<<<dim3(4, kBT / 64), 256, 0, stream>>>(XZt, kBT, outw, nullptr, OUT, 256, 256, 512, 0, 1, 0);
        // x = LN(out) + x
        ln_res_kernel<<<kBT, 256, 0, stream>>>(OUT, lng, lnb, X);
    }

    // pooling
    pool_logits_kernel<<<kBT / 4, 256, 0, stream>>>(X, pool_w, pool_b, LG);
    softmax_T_kernel<<<kB, 256, 0, stream>>>(LG);
    hp_kernel<<<kB, 1024, 0, stream>>>(LG, X, HP);

    // heads
    head_kernel<<<kB, 128, 0, stream>>>(HP,
        h_w1, h_b1, h_g1, h_be1, h_w2, h_b2, h_g2, h_be2, h_w3, h_b3,
        c_w1, c_b1, c_g1, c_be1, c_w2, c_b2, out);
}

// Round 4
// 3019.973 us; speedup vs baseline: 3.0112x; 1.4967x over previous
//
#include <hip/hip_runtime.h>
#include <math.h>

// ---- problem constants ----
constexpr int kB   = 8;
constexpr int kT   = 2048;
constexpr int kBT  = kB * kT;      // 16384
constexpr int DM   = 256;          // d_model
constexpr int DI   = 512;          // d_inner
constexpr int DS   = 64;           // d_state
constexpr int DR   = 16;           // dt_rank
constexpr int NF   = 15;           // nfeat
constexpr int HID  = 128;
constexpr int NBUCK= 15;
constexpr int NLAY = 4;
constexpr int DBLW = DR + 2*DS;    // 144

typedef unsigned short ushort;
typedef __attribute__((ext_vector_type(8))) short short8;
typedef __attribute__((ext_vector_type(8))) unsigned short ushort8v;
typedef __attribute__((ext_vector_type(4))) float floatx4;

// ---------- helpers ----------
__device__ __forceinline__ ushort f2bf(float f) {
    unsigned u = __float_as_uint(f);
    unsigned r = (u + 0x7FFFu + ((u >> 16) & 1u)) >> 16;
    return (ushort)r;
}
__device__ __forceinline__ float bf2f(ushort h) {
    return __uint_as_float(((unsigned)h) << 16);
}
__device__ __forceinline__ float wave_sum64(float v) {
#pragma unroll
    for (int off = 32; off > 0; off >>= 1) v += __shfl_xor(v, off, 64);
    return v;
}
__device__ __forceinline__ float wave_max64(float v) {
#pragma unroll
    for (int off = 32; off > 0; off >>= 1) v = fmaxf(v, __shfl_xor(v, off, 64));
    return v;
}
__device__ __forceinline__ float block_sum256(float v, float* red) {
    int tid = threadIdx.x;
    v = wave_sum64(v);
    if ((tid & 63) == 0) red[tid >> 6] = v;
    __syncthreads();
    float r = (red[0] + red[1]) + (red[2] + red[3]);
    __syncthreads();
    return r;
}
__device__ __forceinline__ float block_max256(float v, float* red) {
    int tid = threadIdx.x;
    v = wave_max64(v);
    if ((tid & 63) == 0) red[tid >> 6] = v;
    __syncthreads();
    float r = fmaxf(fmaxf(red[0], red[1]), fmaxf(red[2], red[3]));
    __syncthreads();
    return r;
}
__device__ __forceinline__ float gelu_exact(float x) {
    return 0.5f * x * (1.f + erff(x * 0.7071067811865476f));
}
__device__ __forceinline__ float softplus_f(float x) {
    return fmaxf(x, 0.f) + log1pf(expf(-fabsf(x)));
}
__device__ __forceinline__ float silu_f(float x) {
    return x / (1.f + expf(-x));
}
template<int CTRL>
__device__ __forceinline__ float dpp_add(float v) {
    int t = __builtin_amdgcn_update_dpp(0, __float_as_int(v), CTRL, 0xf, 0xf, true);
    return v + __int_as_float(t);
}

// ---------- fp32 -> bf16 cast ----------
__global__ __launch_bounds__(256) void cast_bf16_kernel(
    const float* __restrict__ src, ushort* __restrict__ dst, int n)
{
    int i = blockIdx.x * 256 + threadIdx.x;
    if (i < n) dst[i] = f2bf(src[i]);
}

// ---------- bp stage 1: bars @ w1^T + b1 -> LN -> gelu -> bf16 ----------
__global__ __launch_bounds__(256) void bp1_kernel(
    const float* __restrict__ bars, const float* __restrict__ w1,
    const float* __restrict__ b1, const float* __restrict__ g1,
    const float* __restrict__ be1, ushort* __restrict__ out)
{
    __shared__ float s_in[NF];
    __shared__ float red[4];
    int row = blockIdx.x, tid = threadIdx.x;
    if (tid < NF) s_in[tid] = bars[row * NF + tid];
    __syncthreads();
    float acc = b1[tid];
#pragma unroll
    for (int k = 0; k < NF; k++) acc += s_in[k] * w1[tid * NF + k];
    float mean = block_sum256(acc, red) * (1.f / 256.f);
    float d = acc - mean;
    float var = block_sum256(d * d, red) * (1.f / 256.f);
    float nv = d * rsqrtf(var + 1e-5f) * g1[tid] + be1[tid];
    out[row * 256 + tid] = f2bf(gelu_exact(nv));
}

// ---------- LN (+bias +mask) -> X fp32 + Xb bf16 ----------
__global__ __launch_bounds__(256) void ln_mask_kernel(
    const float* __restrict__ in, const float* __restrict__ bias,
    const float* __restrict__ g, const float* __restrict__ be,
    const float* __restrict__ mask,
    float* __restrict__ X, ushort* __restrict__ Xb)
{
    __shared__ float red[4];
    int row = blockIdx.x, tid = threadIdx.x;
    float v = in[row * 256 + tid] + bias[tid];
    float mean = block_sum256(v, red) * (1.f / 256.f);
    float d = v - mean;
    float var = block_sum256(d * d, red) * (1.f / 256.f);
    float nv = (d * rsqrtf(var + 1e-5f) * g[tid] + be[tid]) * mask[row];
    X[row * 256 + tid] = nv;
    Xb[row * 256 + tid] = f2bf(nv);
}

// ---------- transpose-LN + residual: X[bt][f] += LN(OUTt[:,bt])[f] ----------
__global__ __launch_bounds__(256) void ln_rest_kernel(
    const float* __restrict__ OUTt, const float* __restrict__ g,
    const float* __restrict__ be, float* __restrict__ X,
    ushort* __restrict__ Xb)
{
    __shared__ float red[4][64];
    int lane = threadIdx.x & 63;
    int fg = threadIdx.x >> 6;
    int bt = blockIdx.x * 64 + lane;
    float v[64];
    float s = 0.f;
    const float* src = OUTt + (size_t)(fg * 64) * kBT + bt;
#pragma unroll
    for (int i = 0; i < 64; i++) { v[i] = src[(size_t)i * kBT]; s += v[i]; }
    red[fg][lane] = s;
    __syncthreads();
    float mean = (red[0][lane] + red[1][lane] + red[2][lane] + red[3][lane]) * (1.f / 256.f);
    __syncthreads();
    float s2 = 0.f;
#pragma unroll
    for (int i = 0; i < 64; i++) { float d = v[i] - mean; s2 += d * d; }
    red[fg][lane] = s2;
    __syncthreads();
    float var = (red[0][lane] + red[1][lane] + red[2][lane] + red[3][lane]) * (1.f / 256.f);
    float rs = rsqrtf(var + 1e-5f);
    float* xr = X + (size_t)bt * 256 + fg * 64;
    ushort* xbr = Xb + (size_t)bt * 256 + fg * 64;
#pragma unroll
    for (int i = 0; i < 64; i++) {
        float nv = (v[i] - mean) * rs * g[fg * 64 + i] + be[fg * 64 + i];
        float nx = nv + xr[i];
        xr[i] = nx;
        xbr[i] = f2bf(nx);
    }
}

// ---------- bf16 MFMA GEMM: D[r][c] = sum_k P[r][k] * Qe[c][k] ----------
// P: [R][K] bf16 row-major (ldp=K). QMODE 0: Q = [Ctot][K] (ldq=K).
// QMODE 1: Q = [K][Ctot] (ldq=Ctot) -> transposed during LDS staging.
// D fp32 [R][ldd]. Block tile 128(R) x 64(C), BK=64, 4 waves.
template<int QMODE>
__global__ __launch_bounds__(256) void gemm_mfma(
    const ushort* __restrict__ P, int ldp,
    const ushort* __restrict__ Q, int ldq,
    float* __restrict__ D, int ldd,
    int R, int K)
{
    __shared__ __align__(16) ushort Plds[128 * 72];
    __shared__ __align__(16) ushort Qlds[64 * 72];
    int tid = threadIdx.x;
    int lane = tid & 63;
    int w = tid >> 6;
    int wr = w >> 1, wc = w & 1;
    int quad = lane >> 4, l15 = lane & 15;
    int c0 = blockIdx.x * 64;
    int r0 = blockIdx.y * 128;

    floatx4 acc[4][2];
#pragma unroll
    for (int i = 0; i < 4; i++)
#pragma unroll
        for (int j = 0; j < 2; j++)
#pragma unroll
            for (int r = 0; r < 4; r++) acc[i][j][r] = 0.f;

    for (int kb = 0; kb < K; kb += 64) {
#pragma unroll
        for (int i = 0; i < 4; i++) {
            int idx = i * 256 + tid;
            int r = idx >> 3, ch = idx & 7;
            int gr = r0 + r; if (gr > R - 1) gr = R - 1;
            ushort8v v = *(const ushort8v*)(P + (size_t)gr * ldp + kb + ch * 8);
            *(ushort8v*)(Plds + r * 72 + ch * 8) = v;
        }
        if (QMODE == 0) {
#pragma unroll
            for (int i = 0; i < 2; i++) {
                int idx = i * 256 + tid;
                int c = idx >> 3, ch = idx & 7;
                ushort8v v = *(const ushort8v*)(Q + (size_t)(c0 + c) * ldq + kb + ch * 8);
                *(ushort8v*)(Qlds + c * 72 + ch * 8) = v;
            }
        } else {
#pragma unroll
            for (int i = 0; i < 2; i++) {
                int idx = i * 256 + tid;
                int kk = idx >> 3, ch = idx & 7;
                ushort8v v = *(const ushort8v*)(Q + (size_t)(kb + kk) * ldq + c0 + ch * 8);
#pragma unroll
                for (int jj = 0; jj < 8; jj++)
                    Qlds[(ch * 8 + jj) * 72 + kk] = v[jj];
            }
        }
        __syncthreads();
#pragma unroll
        for (int ks = 0; ks < 2; ks++) {
            int ko = ks * 32 + quad * 8;
            short8 b0v = *(const short8*)(Qlds + (wc * 32 + l15) * 72 + ko);
            short8 b1v = *(const short8*)(Qlds + (wc * 32 + 16 + l15) * 72 + ko);
#pragma unroll
            for (int i = 0; i < 4; i++) {
                short8 av = *(const short8*)(Plds + (wr * 64 + i * 16 + l15) * 72 + ko);
                acc[i][0] = __builtin_amdgcn_mfma_f32_16x16x32_bf16(av, b0v, acc[i][0], 0, 0, 0);
                acc[i][1] = __builtin_amdgcn_mfma_f32_16x16x32_bf16(av, b1v, acc[i][1], 0, 0, 0);
            }
        }
        __syncthreads();
    }
#pragma unroll
    for (int i = 0; i < 4; i++) {
        int rbase = r0 + wr * 64 + i * 16 + quad * 4;
#pragma unroll
        for (int j = 0; j < 2; j++) {
            int c = c0 + wc * 32 + j * 16 + l15;
#pragma unroll
            for (int reg = 0; reg < 4; reg++) {
                int rr = rbase + reg;
                if (rr < R) D[(size_t)rr * ldd + c] = acc[i][j][reg];
            }
        }
    }
}

// ---------- fp32 tiled GEMM (dt path only): transA + transC + softplus ----------
__global__ __launch_bounds__(256) void gemm_nt(
    const float* __restrict__ A, int lda,
    const float* __restrict__ W,
    const float* __restrict__ bias,
    float* __restrict__ C, int ldc,
    int N, int K, int act, int transA, int transC)
{
    __shared__ float As[64][17];
    __shared__ float Ws[64][17];
    int tid = threadIdx.x;
    int tx = tid & 15, ty = tid >> 4;
    int bm = blockIdx.y * 64, bn = blockIdx.x * 64;
    float acc[4][4] = {};
    for (int kb = 0; kb < K; kb += 16) {
        if (transA) {
#pragma unroll
            for (int i = 0; i < 4; i++) {
                int idx = i * 256 + tid;
                int r = idx & 63, kk = idx >> 6;
                As[r][kk] = A[(kb + kk) * (size_t)lda + bm + r];
            }
        } else {
#pragma unroll
            for (int i = 0; i < 4; i++) {
                int idx = i * 256 + tid;
                int r = idx >> 4, kk = idx & 15;
                As[r][kk] = A[(bm + r) * (size_t)lda + kb + kk];
            }
        }
#pragma unroll
        for (int i = 0; i < 4; i++) {
            int idx = i * 256 + tid;
            int r = idx >> 4, kk = idx & 15;
            int n = bn + r;
            Ws[r][kk] = (n < N) ? W[n * (size_t)K + kb + kk] : 0.f;
        }
        __syncthreads();
#pragma unroll
        for (int kk = 0; kk < 16; kk++) {
            float a0 = As[ty][kk], a1 = As[ty + 16][kk], a2 = As[ty + 32][kk], a3 = As[ty + 48][kk];
            float w0 = Ws[tx][kk], w1 = Ws[tx + 16][kk], w2 = Ws[tx + 32][kk], w3 = Ws[tx + 48][kk];
            acc[0][0] += a0 * w0; acc[0][1] += a0 * w1; acc[0][2] += a0 * w2; acc[0][3] += a0 * w3;
            acc[1][0] += a1 * w0; acc[1][1] += a1 * w1; acc[1][2] += a1 * w2; acc[1][3] += a1 * w3;
            acc[2][0] += a2 * w0; acc[2][1] += a2 * w1; acc[2][2] += a2 * w2; acc[2][3] += a2 * w3;
            acc[3][0] += a3 * w0; acc[3][1] += a3 * w1; acc[3][2] += a3 * w2; acc[3][3] += a3 * w3;
        }
        __syncthreads();
    }
#pragma unroll
    for (int i = 0; i < 4; i++) {
        int row = bm + ty + i * 16;
#pragma unroll
        for (int j = 0; j < 4; j++) {
            int col = bn + tx + j * 16;
            if (col < N) {
                float v = acc[i][j];
                if (bias) v += bias[col];
                if (act == 1) v = softplus_f(v);
                if (transC) C[(size_t)col * ldc + row] = v;
                else        C[(size_t)row * ldc + col] = v;
            }
        }
    }
}

// ---------- depthwise causal conv(4) + bias + silu, [d][bt] layout ----------
__global__ __launch_bounds__(256) void conv_silu_kernel(
    const float* __restrict__ XT, const float* __restrict__ cw,
    const float* __restrict__ cb, float* __restrict__ XCt)
{
    int idx = blockIdx.x * 256 + threadIdx.x;   // d*kBT + bt
    int bt = idx & (kBT - 1);
    int d  = idx >> 14;
    int t  = bt & (kT - 1);
    float acc = cb[d];
    const float* xr = XT + (size_t)d * kBT + bt;
#pragma unroll
    for (int k = 0; k < 4; k++) {
        int tt = t + k - 3;
        if (tt >= 0) acc += xr[k - 3] * cw[d * 4 + k];
    }
    XCt[idx] = silu_f(acc);
}

// ---------- transpose + cast: src fp32 [512][kBT] -> dst bf16 [kBT][512] ----------
__global__ __launch_bounds__(256) void transpose_cast_kernel(
    const float* __restrict__ src, ushort* __restrict__ dst)
{
    __shared__ float tile[64][65];
    int t = threadIdx.x;
    int c0 = blockIdx.x * 64;   // bt
    int r0 = blockIdx.y * 64;   // d
#pragma unroll
    for (int i = 0; i < 16; i++) {
        int idx = i * 256 + t;
        int r = idx >> 6, c = idx & 63;
        tile[r][c] = src[(size_t)(r0 + r) * kBT + c0 + c];
    }
    __syncthreads();
    int c = t >> 2, rch = t & 3;
    ushort tmp[16];
#pragma unroll
    for (int q = 0; q < 16; q++) tmp[q] = f2bf(tile[rch * 16 + q][c]);
    ushort* dp = dst + (size_t)(c0 + c) * DI + r0 + rch * 16;
    *(ushort8v*)(dp) = *(ushort8v*)(tmp);
    *(ushort8v*)(dp + 8) = *(ushort8v*)(tmp + 8);
}

// ---------- selective scan: one wave per (b,d), lane = state ----------
constexpr int CH = 8;
__global__ __launch_bounds__(256) void scan_kernel(
    const float* __restrict__ DTt, const float* __restrict__ XCt,
    const float* __restrict__ DBLt, const float* __restrict__ Alog,
    const float* __restrict__ Dp,
    const float* __restrict__ ZT, ushort* __restrict__ Yb)
{
    int wid = blockIdx.x * 4 + (threadIdx.x >> 6);   // 0..4095
    int lane = threadIdx.x & 63;
    int b = wid >> 9;
    int d = wid & (DI - 1);
    float a2 = -expf(Alog[d * DS + lane]) * 1.4426950408889634f;
    float Dd = Dp[d];
    unsigned off = (unsigned)__builtin_amdgcn_readfirstlane(d * kBT + b * kT);
    const float* dtp = DTt + off;
    const float* xp  = XCt + off;
    const float* Bp  = DBLt + (size_t)(DR + lane) * kBT + b * kT;
    const float* Cp  = DBLt + (size_t)(DR + DS + lane) * kBT + b * kT;
    const float* xq  = xp + (lane & 7);
    const float* zq  = ZT + off + (lane & 7);
    ushort* yq = Yb + off + lane;   // lanes 0-7 store
    bool b0 = (lane & 1) != 0, b1 = (lane & 2) != 0, b2 = (lane & 4) != 0;
    float h = 0.f;

    float4 dta = *(const float4*)(dtp),     dtb = *(const float4*)(dtp + 4);
    float4 xa  = *(const float4*)(xp),      xb  = *(const float4*)(xp + 4);
    float4 Ba  = *(const float4*)(Bp),      Bb  = *(const float4*)(Bp + 4);
    float4 Ca  = *(const float4*)(Cp),      Cb  = *(const float4*)(Cp + 4);
    float  zP  = zq[0], xP = xq[0];

    for (int t0 = 0; t0 < kT; t0 += CH) {
        int t1 = (t0 + CH < kT) ? (t0 + CH) : t0;
        float4 ndta = *(const float4*)(dtp + t1), ndtb = *(const float4*)(dtp + t1 + 4);
        float4 nxa  = *(const float4*)(xp + t1),  nxb  = *(const float4*)(xp + t1 + 4);
        float4 nBa  = *(const float4*)(Bp + t1),  nBb  = *(const float4*)(Bp + t1 + 4);
        float4 nCa  = *(const float4*)(Cp + t1),  nCb  = *(const float4*)(Cp + t1 + 4);
        float  nzP  = zq[t1], nxP = xq[t1];

        float dts[8] = {dta.x, dta.y, dta.z, dta.w, dtb.x, dtb.y, dtb.z, dtb.w};
        float xs[8]  = {xa.x,  xa.y,  xa.z,  xa.w,  xb.x,  xb.y,  xb.z,  xb.w};
        float Bs[8]  = {Ba.x,  Ba.y,  Ba.z,  Ba.w,  Bb.x,  Bb.y,  Bb.z,  Bb.w};
        float Cs[8]  = {Ca.x,  Ca.y,  Ca.z,  Ca.w,  Cb.x,  Cb.y,  Cb.z,  Cb.w};
        float p[8];
#pragma unroll
        for (int j = 0; j < 8; j++) {
            float dA = exp2f(dts[j] * a2);
            h = fmaf(dA, h, (dts[j] * xs[j]) * Bs[j]);
            p[j] = h * Cs[j];
        }
#pragma unroll
        for (int j = 0; j < 8; j++) p[j] = dpp_add<0x121>(p[j]);
#pragma unroll
        for (int j = 0; j < 8; j++) p[j] = dpp_add<0x122>(p[j]);
#pragma unroll
        for (int j = 0; j < 8; j++) p[j] = dpp_add<0x124>(p[j]);
#pragma unroll
        for (int j = 0; j < 8; j++) p[j] = dpp_add<0x128>(p[j]);
#pragma unroll
        for (int j = 0; j < 8; j++) p[j] += __shfl_xor(p[j], 16, 64);
#pragma unroll
        for (int j = 0; j < 8; j++) p[j] += __shfl_xor(p[j], 32, 64);
        float m01 = b0 ? p[1] : p[0];
        float m23 = b0 ? p[3] : p[2];
        float m45 = b0 ? p[5] : p[4];
        float m67 = b0 ? p[7] : p[6];
        float m0123 = b1 ? m23 : m01;
        float m4567 = b1 ? m67 : m45;
        float pP = b2 ? m4567 : m0123;
        float y = fmaf(xP, Dd, pP) * (zP / (1.f + __expf(-zP)));
        if (lane < 8) yq[t0] = f2bf(y);

        dta = ndta; dtb = ndtb; xa = nxa; xb = nxb;
        Ba = nBa; Bb = nBb; Ca = nCa; Cb = nCb; zP = nzP; xP = nxP;
    }
}

// ---------- pooling ----------
__global__ __launch_bounds__(256) void pool_logits_kernel(
    const float* __restrict__ X, const float* __restrict__ pw,
    const float* __restrict__ pb, float* __restrict__ LG)
{
    int wid = blockIdx.x * 4 + (threadIdx.x >> 6);
    int lane = threadIdx.x & 63;
    float acc = 0.f;
#pragma unroll
    for (int c = 0; c < 4; c++) {
        int k = lane + 64 * c;
        acc += X[(size_t)wid * 256 + k] * pw[k];
    }
    acc = wave_sum64(acc);
    if (lane == 0) LG[wid] = acc + pb[0];
}

__global__ __launch_bounds__(256) void softmax_T_kernel(float* __restrict__ LG)
{
    __shared__ float red[4];
    int b = blockIdx.x, tid = threadIdx.x;
    float l[8];
    float m = -1e30f;
#pragma unroll
    for (int c = 0; c < 8; c++) {
        l[c] = LG[b * kT + tid + 256 * c];
        m = fmaxf(m, l[c]);
    }
    m = block_max256(m, red);
    float s = 0.f;
#pragma unroll
    for (int c = 0; c < 8; c++) { l[c] = expf(l[c] - m); s += l[c]; }
    s = block_sum256(s, red);
    float inv = 1.f / s;
#pragma unroll
    for (int c = 0; c < 8; c++) LG[b * kT + tid + 256 * c] = l[c] * inv;
}

__global__ __launch_bounds__(1024) void hp_kernel(
    const float* __restrict__ WTS, const float* __restrict__ X,
    float* __restrict__ HP)
{
    __shared__ float part[4][256];
    int b = blockIdx.x;
    int n = threadIdx.x & 255, c = threadIdx.x >> 8;
    float acc = 0.f;
    int t0 = c * 512;
    for (int t = t0; t < t0 + 512; t++) {
        int bt = b * kT + t;
        acc += WTS[bt] * X[(size_t)bt * 256 + n];
    }
    part[c][n] = acc;
    __syncthreads();
    if (c == 0) HP[b * 256 + n] = part[0][n] + part[1][n] + part[2][n] + part[3][n];
}

// ---------- heads ----------
__device__ __forceinline__ float ln128_gelu(float v, const float* g, const float* be, float* red)
{
    int tid = threadIdx.x;
    red[tid] = v; __syncthreads();
#pragma unroll
    for (int s = 64; s > 0; s >>= 1) { if (tid < s) red[tid] += red[tid + s]; __syncthreads(); }
    float mean = red[0] * (1.f / 128.f); __syncthreads();
    float d = v - mean;
    red[tid] = d * d; __syncthreads();
#pragma unroll
    for (int s = 64; s > 0; s >>= 1) { if (tid < s) red[tid] += red[tid + s]; __syncthreads(); }
    float var = red[0] * (1.f / 128.f); __syncthreads();
    float nv = d * rsqrtf(var + 1e-5f) * g[tid] + be[tid];
    return gelu_exact(nv);
}

__global__ __launch_bounds__(128) void head_kernel(
    const float* __restrict__ HP,
    const float* __restrict__ h_w1, const float* __restrict__ h_b1,
    const float* __restrict__ h_g1, const float* __restrict__ h_be1,
    const float* __restrict__ h_w2, const float* __restrict__ h_b2,
    const float* __restrict__ h_g2, const float* __restrict__ h_be2,
    const float* __restrict__ h_w3, const float* __restrict__ h_b3,
    const float* __restrict__ c_w1, const float* __restrict__ c_b1,
    const float* __restrict__ c_g1, const float* __restrict__ c_be1,
    const float* __restrict__ c_w2, const float* __restrict__ c_b2,
    float* __restrict__ out)
{
    __shared__ float s_hp[256];
    __shared__ float s1[128];
    __shared__ float red[128];
    int b = blockIdx.x, tid = threadIdx.x;
    s_hp[tid] = HP[b * 256 + tid];
    s_hp[tid + 128] = HP[b * 256 + tid + 128];
    __syncthreads();

    float v = h_b1[tid];
    for (int k = 0; k < 256; k++) v += s_hp[k] * h_w1[tid * 256 + k];
    float g1v = ln128_gelu(v, h_g1, h_be1, red);
    s1[tid] = g1v;
    __syncthreads();

    float v2 = h_b2[tid];
    for (int k = 0; k < 128; k++) v2 += s1[k] * h_w2[tid * 128 + k];
    float g2v = ln128_gelu(v2, h_g2, h_be2, red);

    red[tid] = g2v * h_w3[tid];
    __syncthreads();
#pragma unroll
    for (int s = 64; s > 0; s >>= 1) { if (tid < s) red[tid] += red[tid + s]; __syncthreads(); }
    if (tid == 0) out[b] = red[0] + h_b3[0];
    __syncthreads();

    float vc = c_b1[tid];
    for (int k = 0; k < 256; k++) vc += s_hp[k] * c_w1[tid * 256 + k];
    float gcv = ln128_gelu(vc, c_g1, c_be1, red);
    s1[tid] = gcv;
    __syncthreads();
    if (tid < NBUCK) {
        float acc = c_b2[tid];
        for (int k = 0; k < 128; k++) acc += s1[k] * c_w2[tid * 128 + k];
        out[8 + b * NBUCK + tid] = acc;
    }
}

// ---------- launch ----------
extern "C" void kernel_launch(void* const* d_in, const int* in_sizes, int n_in,
                              void* d_out, int out_size, void* d_ws, size_t ws_size,
                              hipStream_t stream)
{
    const float* bars     = (const float*)d_in[0];
    const float* bar_mask = (const float*)d_in[1];
    const float* bp_w1    = (const float*)d_in[2];
    const float* bp_b1    = (const float*)d_in[3];
    const float* bp_g1    = (const float*)d_in[4];
    const float* bp_be1   = (const float*)d_in[5];
    const float* bp_w2    = (const float*)d_in[6];
    const float* bp_b2    = (const float*)d_in[7];
    const float* bp_g2    = (const float*)d_in[8];
    const float* bp_be2   = (const float*)d_in[9];
    const float* m_in_w   = (const float*)d_in[10];
    const float* m_conv_w = (const float*)d_in[11];
    const float* m_conv_b = (const float*)d_in[12];
    const float* m_xproj_w= (const float*)d_in[13];
    const float* m_dt_w   = (const float*)d_in[14];
    const float* m_dt_b   = (const float*)d_in[15];
    const float* m_Alog   = (const float*)d_in[16];
    const float* m_D      = (const float*)d_in[17];
    const float* m_out_w  = (const float*)d_in[18];
    const float* m_ln_g   = (const float*)d_in[19];
    const float* m_ln_b   = (const float*)d_in[20];
    const float* pool_w   = (const float*)d_in[21];
    const float* pool_b   = (const float*)d_in[22];
    const float* h_w1     = (const float*)d_in[23];
    const float* h_b1     = (const float*)d_in[24];
    const float* h_g1     = (const float*)d_in[25];
    const float* h_be1    = (const float*)d_in[26];
    const float* h_w2     = (const float*)d_in[27];
    const float* h_b2     = (const float*)d_in[28];
    const float* h_g2     = (const float*)d_in[29];
    const float* h_be2    = (const float*)d_in[30];
    const float* h_w3     = (const float*)d_in[31];
    const float* h_b3     = (const float*)d_in[32];
    const float* c_w1     = (const float*)d_in[33];
    const float* c_b1     = (const float*)d_in[34];
    const float* c_g1     = (const float*)d_in[35];
    const float* c_be1    = (const float*)d_in[36];
    const float* c_w2     = (const float*)d_in[37];
    const float* c_b2     = (const float*)d_in[38];
    float* out = (float*)d_out;

    float* ws = (float*)d_ws;
    float* X    = ws;                          // [kBT][256] fp32           4.19M
    float* XZt  = X    + (size_t)kBT * 256;    // [1024][kBT] fp32         16.78M
    float* XCt  = XZt  + (size_t)1024 * kBT;   // [512][kBT] fp32           8.39M
    float* DBLt = XCt  + (size_t)512 * kBT;    // [144][kBT] fp32           2.36M
    float* DTt  = DBLt + (size_t)DBLW * kBT;   // [512][kBT] fp32           8.39M
    float* OUTt = DTt  + (size_t)512 * kBT;    // [256][kBT] fp32 (also bp2 D as [kBT][256])
    float* LG   = OUTt + (size_t)256 * kBT;    // kBT
    float* HP   = LG   + (size_t)kBT;          // kB*256
    float* fend = HP   + kB * 256;
    ushort* Xb   = (ushort*)fend;                        // [kBT][256] bf16 (2.10M fl)
    ushort* inwb = (ushort*)(fend + 2097152);            // 4*1024*256   (0.52M fl)
    ushort* xpwb = inwb + (size_t)NLAY * 1024 * 256;     // 4*144*512    (0.15M fl)
    ushort* outwb= xpwb + (size_t)NLAY * DBLW * 512;     // 4*256*512    (0.26M fl)
    ushort* w2b  = outwb + (size_t)NLAY * 256 * 512;     // 256*256
    // aliases (lifetimes disjoint):
    ushort* bp1b = (ushort*)DTt;       // [kBT][256] bf16, dead before first conv
    ushort* XCb  = (ushort*)DTt;       // [kBT][512] bf16, dead before dt-gemm writes DTt
    ushort* Yb   = (ushort*)XZt;       // [512][kBT] bf16, overwrites x-half after conv
    float*  BP2D = OUTt;               // [kBT][256] fp32, dead after ln_mask

    // weight casts (bf16)
    cast_bf16_kernel<<<(NLAY*1024*256)/256, 256, 0, stream>>>(m_in_w, inwb, NLAY*1024*256);
    cast_bf16_kernel<<<(NLAY*DBLW*512)/256, 256, 0, stream>>>(m_xproj_w, xpwb, NLAY*DBLW*512);
    cast_bf16_kernel<<<(NLAY*256*512)/256, 256, 0, stream>>>(m_out_w, outwb, NLAY*256*512);
    cast_bf16_kernel<<<(256*256)/256, 256, 0, stream>>>(bp_w2, w2b, 256*256);

    // bar projection
    bp1_kernel<<<kBT, 256, 0, stream>>>(bars, bp_w1, bp_b1, bp_g1, bp_be1, bp1b);
    // bp2: D[bt][256] = bp1 @ w2^T
    gemm_mfma<0><<<dim3(4, 128), 256, 0, stream>>>(bp1b, 256, w2b, 256, BP2D, 256, kBT, 256);
    ln_mask_kernel<<<kBT, 256, 0, stream>>>(BP2D, bp_b2, bp_g2, bp_be2, bar_mask, X, Xb);

    for (int i = 0; i < NLAY; i++) {
        const ushort* in_wb = inwb  + (size_t)i * 1024 * 256;
        const ushort* xpwbi = xpwb  + (size_t)i * DBLW * 512;
        const ushort* outwbi= outwb + (size_t)i * 256 * 512;
        const float* cw    = m_conv_w + (size_t)i * DI * 4;
        const float* cb    = m_conv_b + (size_t)i * DI;
        const float* dtw   = m_dt_w   + (size_t)i * DI * DR;
        const float* dtb   = m_dt_b   + (size_t)i * DI;
        const float* alog  = m_Alog   + (size_t)i * DI * DS;
        const float* dp    = m_D      + (size_t)i * DI;
        const float* lng   = m_ln_g   + (size_t)i * DM;
        const float* lnb   = m_ln_b   + (size_t)i * DM;

        // xz^T [1024][kBT] = (in_w) x (Xb rows)
        gemm_mfma<0><<<dim3(256, 8), 256, 0, stream>>>(in_wb, 256, Xb, 256, XZt, kBT, 1024, 256);
        // depthwise conv + silu -> XCt [512][kBT]
        conv_silu_kernel<<<(kBT * DI) / 256, 256, 0, stream>>>(XZt, cw, cb, XCt);
        // bf16 transpose of XCt -> XCb [kBT][512]
        transpose_cast_kernel<<<dim3(256, 8), 256, 0, stream>>>(XCt, XCb);
        // dbl^T [144][kBT]
        gemm_mfma<0><<<dim3(256, 2), 256, 0, stream>>>(xpwbi, 512, XCb, 512, DBLt, kBT, DBLW, 512);
        // dt^T [512][kBT] = softplus(dbl[:, :16] @ dt_w^T + dt_b)^T  (fp32)
        gemm_nt<<<dim3(8, kBT / 64), 256, 0, stream>>>(DBLt, kBT, dtw, dtb, DTt, kBT, 512, 16, 1, 1, 1);
        // scan -> Yb [512][kBT] bf16
        scan_kernel<<<1024, 256, 0, stream>>>(DTt, XCt, DBLt, alog, dp, XZt + (size_t)DI * kBT, Yb);
        // out^T [256][kBT] = out_w x y   (Q transposed mode)
        gemm_mfma<1><<<dim3(256, 2), 256, 0, stream>>>(outwbi, 512, Yb, kBT, OUTt, kBT, 256, 512);
        // X += LN(out)
        ln_rest_kernel<<<kBT / 64, 256, 0, stream>>>(OUTt, lng, lnb, X, Xb);
    }

    // pooling
    pool_logits_kernel<<<kBT / 4, 256, 0, stream>>>(X, pool_w, pool_b, LG);
    softmax_T_kernel<<<kB, 256, 0, stream>>>(LG);
    hp_kernel<<<kB, 1024, 0, stream>>>(LG, X, HP);

    // heads
    head_kernel<<<kB, 128, 0, stream>>>(HP,
        h_w1, h_b1, h_g1, h_be1, h_w2, h_b2, h_g2, h_be2, h_w3, h_b3,
        c_w1, c_b1, c_g1, c_be1, c_w2, c_b2, out);
}